// Round 10
// baseline (437.458 us; speedup 1.0000x reference)
//
#include <hip/hip_runtime.h>
#include <math.h>

typedef unsigned short u16;
typedef __attribute__((ext_vector_type(8))) _Float16 half8;
typedef __attribute__((ext_vector_type(4))) float f32x4;
typedef __attribute__((ext_vector_type(4))) unsigned short us4;

// Inputs f32, output f32 (proven r4-9). Format: f16 single-term (r9 absmax 2.3e-10).

static __device__ __forceinline__ u16 f2h(float f) {
    _Float16 h = (_Float16)f;
    return __builtin_bit_cast(u16, h);
}
static __device__ __forceinline__ float h2f(u16 u) {
    return (float)__builtin_bit_cast(_Float16, u);
}
// async global->LDS DMA, 16B/lane; lds base must be wave-uniform (HW adds lane*16)
static __device__ __forceinline__ void gl_lds16(const void* g, void* l) {
    __builtin_amdgcn_global_load_lds(
        (const __attribute__((address_space(1))) void*)g,
        (__attribute__((address_space(3))) void*)l, 16, 0, 0);
}

// ---------- weight transpose: WT[w][n][k] = f16(W[w][k][n]) ----------
__global__ __launch_bounds__(256) void transpose_w(
    const float* __restrict__ Wq, const float* __restrict__ Wk, const float* __restrict__ Wv,
    const float* __restrict__ Wg, const float* __restrict__ Wo, const float* __restrict__ W1,
    const float* __restrict__ W2, u16* __restrict__ WT)
{
    __shared__ float tile[64][65];
    const float* Ws[7] = {Wq, Wk, Wv, Wg, Wo, W1, W2};
    int w = blockIdx.z;
    int k0 = blockIdx.x * 64, n0 = blockIdx.y * 64;
    const float* W = Ws[w];
    int t = threadIdx.x;
    for (int c = t; c < 4096; c += 256) {
        int row = c >> 6, col = c & 63;
        tile[row][col] = W[(size_t)(k0 + row) * 512 + n0 + col];
    }
    __syncthreads();
    for (int c = t; c < 4096; c += 256) {
        int row = c >> 6, col = c & 63;
        WT[(size_t)w * 262144 + (size_t)(n0 + row) * 512 + k0 + col] = f2h(tile[col][row]);
    }
}

// ---------- LayerNorm; optional f32/f16 outputs; optional fused FC dot (mode fcW) ----------
__global__ __launch_bounds__(256) void ln_kernel(
    const float* __restrict__ xin,
    const int* __restrict__ ids, const float* __restrict__ emb, const float* __restrict__ pos,
    const float* __restrict__ gam, const float* __restrict__ bet,
    float* __restrict__ outf, u16* __restrict__ outh, int mode, float* __restrict__ zero8,
    const float* __restrict__ fcW, float* __restrict__ logits)
{
    __shared__ float red[8];
    __shared__ float red2[4];
    int row = blockIdx.x, t = threadIdx.x;
    int wid = t >> 6, lane = t & 63;
    float v0, v1;
    if (mode == 1) {
        int id = ids[2 * 8192 + row];
        const float* e = emb + (size_t)(2 * 1024 + id) * 512;
        const float* p = pos + (size_t)(2 * 1024 + (row & 1023)) * 512;
        v0 = e[t] + p[t];
        v1 = e[t + 256] + p[t + 256];
    } else {
        v0 = xin[(size_t)row * 512 + t];
        v1 = xin[(size_t)row * 512 + t + 256];
    }
    float s1 = v0 + v1, s2 = v0 * v0 + v1 * v1;
#pragma unroll
    for (int o = 32; o >= 1; o >>= 1) {
        s1 += __shfl_xor(s1, o, 64);
        s2 += __shfl_xor(s2, o, 64);
    }
    if (lane == 0) { red[wid] = s1; red[4 + wid] = s2; }
    __syncthreads();
    float S1 = red[0] + red[1] + red[2] + red[3];
    float S2 = red[4] + red[5] + red[6] + red[7];
    float mu = S1 * (1.f / 512.f);
    float var = fmaxf(S2 * (1.f / 512.f) - mu * mu, 0.f);
    float rs = 1.f / sqrtf(var + 1e-5f);
    float y0 = (v0 - mu) * rs * gam[t] + bet[t];
    float y1 = (v1 - mu) * rs * gam[t + 256] + bet[t + 256];
    if (outf) {
        outf[(size_t)row * 512 + t] = y0;
        outf[(size_t)row * 512 + t + 256] = y1;
    }
    if (outh) {
        outh[(size_t)row * 512 + t] = f2h(y0);
        outh[(size_t)row * 512 + t + 256] = f2h(y1);
    }
    if (fcW) {  // fused final FC: dot row of LN output with fc_W, accumulate per-batch logit
        int srow = row & 1023;
        float d = y0 * fcW[(size_t)srow * 512 + t] + y1 * fcW[(size_t)srow * 512 + t + 256];
#pragma unroll
        for (int o = 32; o >= 1; o >>= 1) d += __shfl_xor(d, o, 64);
        if (lane == 0) red2[wid] = d;
        __syncthreads();
        if (t == 0) atomicAdd(&logits[row >> 10], red2[0] + red2[1] + red2[2] + red2[3]);
    }
    if (zero8 && row == 0 && t < 8) zero8[t] = 0.f;
}

// ---------- GEMM: C = A_f16 x B_f16^T ; global_load_lds staging, unpadded BK=32 LDS ----------
// mode 0: outf=C ; 1: outf=C+res ; 2: outh=f16(relu(C+bias)) ; 3: outf=C+bias+res ;
// 4: outh=f16(C) at ostride
__global__ __launch_bounds__(256) void gemm_f16(
    const u16* __restrict__ A2, const u16* __restrict__ Bg,
    float* __restrict__ outf, u16* __restrict__ outh,
    const float* __restrict__ res, const float* __restrict__ bias, int mode, int ostride)
{
    __shared__ u16 As[128 * 32];   // unpadded: matches global_load_lds lane*16B layout (m97)
    __shared__ u16 Bs[128 * 32];
    int t = threadIdx.x;
    int wid = t >> 6, lane = t & 63, quad = lane >> 4, l15 = lane & 15;
    int wm = wid >> 1, wn = wid & 1;
    int m0 = blockIdx.y * 128, n0 = blockIdx.x * 128;

    // staging map: lane -> (row = wid*16 + lane>>2, part = lane&3), 2 halves of 64 rows
    int srow = wid * 16 + (lane >> 2);
    int spart = (lane & 3) * 8;
    u16* ldsA0 = &As[(wid * 16) * 32];
    u16* ldsA1 = &As[(64 + wid * 16) * 32];
    u16* ldsB0 = &Bs[(wid * 16) * 32];
    u16* ldsB1 = &Bs[(64 + wid * 16) * 32];

    f32x4 acc[4][4];
#pragma unroll
    for (int a = 0; a < 4; ++a)
#pragma unroll
        for (int b = 0; b < 4; ++b) acc[a][b] = (f32x4){0.f, 0.f, 0.f, 0.f};

    for (int ki = 0; ki < 16; ++ki) {
        int k0 = ki * 32;
        __syncthreads();
        gl_lds16(&A2[(size_t)(m0 + srow) * 512 + k0 + spart], ldsA0);
        gl_lds16(&A2[(size_t)(m0 + 64 + srow) * 512 + k0 + spart], ldsA1);
        gl_lds16(&Bg[(size_t)(n0 + srow) * 512 + k0 + spart], ldsB0);
        gl_lds16(&Bg[(size_t)(n0 + 64 + srow) * 512 + k0 + spart], ldsB1);
        __syncthreads();
        half8 af[4], bf[4];
#pragma unroll
        for (int tm = 0; tm < 4; ++tm)
            af[tm] = *(const half8*)&As[(wm * 64 + tm * 16 + l15) * 32 + quad * 8];
#pragma unroll
        for (int tn = 0; tn < 4; ++tn)
            bf[tn] = *(const half8*)&Bs[(wn * 64 + tn * 16 + l15) * 32 + quad * 8];
#pragma unroll
        for (int tm = 0; tm < 4; ++tm)
#pragma unroll
            for (int tn = 0; tn < 4; ++tn)
                acc[tm][tn] = __builtin_amdgcn_mfma_f32_16x16x32_f16(af[tm], bf[tn], acc[tm][tn], 0, 0, 0);
    }

#pragma unroll
    for (int tm = 0; tm < 4; ++tm) {
#pragma unroll
        for (int tn = 0; tn < 4; ++tn) {
            int n = n0 + wn * 64 + tn * 16 + l15;
            int mbase = m0 + wm * 64 + tm * 16 + quad * 4;
#pragma unroll
            for (int r = 0; r < 4; ++r) {
                int m = mbase + r;
                float v = acc[tm][tn][r];
                if (mode == 1) v += res[(size_t)m * 512 + n];
                else if (mode == 2) v = fmaxf(v + bias[n], 0.f);
                else if (mode == 3) v += bias[n] + res[(size_t)m * 512 + n];
                if (mode == 2) outh[(size_t)m * 512 + n] = f2h(v);
                else if (mode == 4) outh[(size_t)m * ostride + n] = f2h(v);
                else outf[(size_t)m * ostride + n] = v;
            }
        }
    }
}

// ---------- fused retention, q-tile=128, m-tile=128 (halved barrier count vs r9) ----------
__global__ __launch_bounds__(256) void retention_f16(
    const u16* __restrict__ QKVGh, u16* __restrict__ Zh)
{
    __shared__ u16 kh[128 * 72];       // K tile [m][d], stride 72
    __shared__ u16 vth[64 * 144];      // V^T [d][m=128], stride 144, rotation-swizzled
    __shared__ u16 ph[4][32 * 136];    // per-wave P [qrow 32][m 128], stride 136

    int t = threadIdx.x;
    int wid = t >> 6, lane = t & 63, quad = lane >> 4, l15 = lane & 15;
    int bh = (blockIdx.x >> 3) & 63;
    int qtr = blockIdx.x & 7;
    int b = bh >> 3, h = bh & 7;
    int qt = ((blockIdx.x >> 8) & 1) ? (7 - qtr) : qtr;  // pairing balance
    int n0 = qt * 128;

    float gamma = 1.f - exp2f(-(float)(5 + h));
    float l2g = log2f(gamma);

    // Q frags (A-layout row=l15, k=quad*8+j), 2 groups of 16 q-rows per wave
    half8 aH[2][2];
#pragma unroll
    for (int g = 0; g < 2; ++g) {
        int qrow = b * 1024 + n0 + wid * 32 + g * 16 + l15;
        const u16* qp = QKVGh + (size_t)qrow * 2048 + h * 64;
#pragma unroll
        for (int ks = 0; ks < 2; ++ks)
            aH[g][ks] = *(const half8*)&qp[ks * 32 + quad * 8];
    }

    f32x4 yacc[2][4];
#pragma unroll
    for (int g = 0; g < 2; ++g)
#pragma unroll
        for (int dt = 0; dt < 4; ++dt) yacc[g][dt] = (f32x4){0.f, 0.f, 0.f, 0.f};

    for (int mt = 0; mt <= qt; ++mt) {
        __syncthreads();
        // K tile 128x64: us4 copies
        for (int c = t; c < 2048; c += 256) {
            int row = c >> 4, c4 = c & 15;
            size_t grow = (size_t)(b * 1024 + mt * 128 + row) * 2048;
            *(us4*)&kh[row * 72 + c4 * 4] = *(const us4*)&QKVGh[grow + 512 + h * 64 + c4 * 4];
        }
        // V^T tile: element (d,m) at d*144 + (((m>>3)+d)&15)*8 + (m&7)
        for (int c = t; c < 2048; c += 256) {
            int d = c & 63, mseg = c >> 6;   // mseg 0..31 (4 m per seg)
            size_t gbase = (size_t)(b * 1024 + mt * 128 + mseg * 4) * 2048 + 1024 + h * 64 + d;
            us4 v4 = {QKVGh[gbase], QKVGh[gbase + 2048],
                      QKVGh[gbase + 4096], QKVGh[gbase + 6144]};
            int base = d * 144 + ((((mseg >> 1)) + d) & 15) * 8 + (mseg & 1) * 4;
            *(us4*)&vth[base] = v4;
        }
        __syncthreads();

        // scores + decay -> P per group (128 m-cols)
#pragma unroll
        for (int g = 0; g < 2; ++g) {
            f32x4 sacc[8];
#pragma unroll
            for (int tn = 0; tn < 8; ++tn) sacc[tn] = (f32x4){0.f, 0.f, 0.f, 0.f};
#pragma unroll
            for (int tn = 0; tn < 8; ++tn)
#pragma unroll
                for (int ks = 0; ks < 2; ++ks) {
                    half8 bH = *(const half8*)&kh[(tn * 16 + l15) * 72 + ks * 32 + quad * 8];
                    sacc[tn] = __builtin_amdgcn_mfma_f32_16x16x32_f16(aH[g][ks], bH, sacc[tn], 0, 0, 0);
                }
#pragma unroll
            for (int tn = 0; tn < 8; ++tn) {
                int mglob = mt * 128 + tn * 16 + l15;                 // D col
#pragma unroll
                for (int r = 0; r < 4; ++r) {
                    int nglob = n0 + wid * 32 + g * 16 + quad * 4 + r;  // D row
                    int diff = nglob - mglob;
                    float p = (diff >= 0) ? sacc[tn][r] * exp2f((float)diff * l2g - 3.0f) : 0.f;
                    ph[wid][(g * 16 + quad * 4 + r) * 136 + tn * 16 + l15] = f2h(p);
                }
            }
        }
        // PV (per-wave P; within-wave DS ordering, no barrier)
#pragma unroll
        for (int g = 0; g < 2; ++g) {
            half8 pH[4];
#pragma unroll
            for (int ks = 0; ks < 4; ++ks)
                pH[ks] = *(const half8*)&ph[wid][(g * 16 + l15) * 136 + ks * 32 + quad * 8];
#pragma unroll
            for (int dt = 0; dt < 4; ++dt) {
                int d = dt * 16 + l15;
#pragma unroll
                for (int ks = 0; ks < 4; ++ks) {
                    half8 vv = *(const half8*)&vth[d * 144 + ((ks * 4 + quad + d) & 15) * 8];
                    yacc[g][dt] = __builtin_amdgcn_mfma_f32_16x16x32_f16(pH[ks], vv, yacc[g][dt], 0, 0, 0);
                }
            }
        }
    }

    // per-q-row groupnorm + swish gate + f16 store
#pragma unroll
    for (int g = 0; g < 2; ++g) {
#pragma unroll
        for (int r = 0; r < 4; ++r) {
            float s1 = yacc[g][0][r] + yacc[g][1][r] + yacc[g][2][r] + yacc[g][3][r];
            float s2 = yacc[g][0][r] * yacc[g][0][r] + yacc[g][1][r] * yacc[g][1][r] +
                       yacc[g][2][r] * yacc[g][2][r] + yacc[g][3][r] * yacc[g][3][r];
#pragma unroll
            for (int o = 1; o <= 8; o <<= 1) {
                s1 += __shfl_xor(s1, o, 64);
                s2 += __shfl_xor(s2, o, 64);
            }
            float mu = s1 * (1.f / 64.f);
            float var = fmaxf(s2 * (1.f / 64.f) - mu * mu, 0.f);
            float rs = 1.f / sqrtf(var + 1e-5f);
            int nglob = n0 + wid * 32 + g * 16 + quad * 4 + r;
            size_t grow = (size_t)(b * 1024 + nglob);
#pragma unroll
            for (int dt = 0; dt < 4; ++dt) {
                int d = dt * 16 + l15;
                float yv = (yacc[g][dt][r] - mu) * rs;
                float gt = h2f(QKVGh[grow * 2048 + 1536 + h * 64 + d]);
                float sw = gt / (1.f + expf(-gt));
                Zh[grow * 512 + h * 64 + d] = f2h(yv * sw);
            }
        }
    }
}

__global__ void fc_final(const float* __restrict__ logits, const float* __restrict__ fcb,
                         float* __restrict__ out)
{
    int t = threadIdx.x;
    if (t < 8) {
        float l = logits[t] + fcb[0];
        out[t] = 1.f / (1.f + expf(-l));
    }
}

extern "C" void kernel_launch(void* const* d_in, const int* in_sizes, int n_in,
                              void* d_out, int out_size, void* d_ws, size_t ws_size,
                              hipStream_t stream)
{
    const int* ids = (const int*)d_in[0];
    const float* emb = (const float*)d_in[1];
    const float* pos = (const float*)d_in[2];
    const float* ln_g = (const float*)d_in[3];
    const float* ln_b = (const float*)d_in[4];
    const float* Wq = (const float*)d_in[5];
    const float* Wk = (const float*)d_in[6];
    const float* Wv = (const float*)d_in[7];
    const float* Wg = (const float*)d_in[8];
    const float* Wo = (const float*)d_in[9];
    const float* W1 = (const float*)d_in[10];
    const float* b1 = (const float*)d_in[11];
    const float* W2 = (const float*)d_in[12];
    const float* b2 = (const float*)d_in[13];
    const float* fcW = (const float*)d_in[14];
    const float* fcb = (const float*)d_in[15];
    float* out = (float*)d_out;

    char* ws = (char*)d_ws;
    u16* WT     = (u16*)(ws);                  //  3,670,016
    float* x0f  = (float*)(ws + 3670016);      // 16,777,216  LN(emb) f32 (residual)
    u16* x0h    = (u16*)(ws + 20447232);       //  8,388,608  LN(emb) f16
    u16* QKVGh  = (u16*)(ws + 28835840);       // 33,554,432  [8192][2048] f16
    float* logits = (float*)(ws + 62390272);   // 32 B (total ~62.4 MB < proven)
    u16* Zh   = x0h;                            // dead after QKVG GEMM
    float* X1 = (float*)QKVGh;                  // QKVGh dead after retention
    u16* Th   = (u16*)((char*)QKVGh + 16777216);
    u16* Hh   = (u16*)((char*)QKVGh + 25165824);
    float* X2 = x0f;                            // dead after Wo-GEMM residual

    // only vocab iteration i=2 is live (x overwritten each pass)
    transpose_w<<<dim3(8, 8, 7), 256, 0, stream>>>(Wq, Wk, Wv, Wg, Wo, W1, W2, WT);
    ln_kernel<<<8192, 256, 0, stream>>>(nullptr, ids, emb, pos, ln_g, ln_b, x0f, x0h, 1, logits, nullptr, nullptr);
    gemm_f16<<<dim3(16, 64), 256, 0, stream>>>(x0h, WT, nullptr, QKVGh, nullptr, nullptr, 4, 2048);
    retention_f16<<<512, 256, 0, stream>>>(QKVGh, Zh);
    gemm_f16<<<dim3(4, 64), 256, 0, stream>>>(Zh, WT + 4 * 262144, X1, nullptr, x0f, nullptr, 1, 512);
    ln_kernel<<<8192, 256, 0, stream>>>(X1, nullptr, nullptr, nullptr, ln_g, ln_b, nullptr, Th, 0, nullptr, nullptr, nullptr);
    gemm_f16<<<dim3(4, 64), 256, 0, stream>>>(Th, WT + 5 * 262144, nullptr, Hh, nullptr, b1, 2, 512);
    gemm_f16<<<dim3(4, 64), 256, 0, stream>>>(Hh, WT + 6 * 262144, X2, nullptr, X1, b2, 3, 512);
    // final LN fused with FC dot (atomicAdd into logits, zeroed by ln1's zero8 arg)
    ln_kernel<<<8192, 256, 0, stream>>>(X2, nullptr, nullptr, nullptr, ln_g, ln_b, nullptr, nullptr, 0, nullptr, fcW, logits);
    fc_final<<<1, 64, 0, stream>>>(logits, fcb, out);
}

// Round 11
// 340.673 us; speedup vs baseline: 1.2841x; 1.2841x over previous
//
#include <hip/hip_runtime.h>
#include <math.h>

typedef unsigned short u16;
typedef __attribute__((ext_vector_type(8))) _Float16 half8;
typedef __attribute__((ext_vector_type(4))) float f32x4;
typedef __attribute__((ext_vector_type(4))) unsigned short us4;

// Inputs f32, output f32 (proven r4-10). Format: f16 single-term (absmax 2.3e-10).

static __device__ __forceinline__ u16 f2h(float f) {
    _Float16 h = (_Float16)f;
    return __builtin_bit_cast(u16, h);
}
static __device__ __forceinline__ float h2f(u16 u) {
    return (float)__builtin_bit_cast(_Float16, u);
}
// async global->LDS DMA, 16B/lane; lds base must be wave-uniform (HW adds lane*16)
static __device__ __forceinline__ void gl_lds16(const void* g, void* l) {
    __builtin_amdgcn_global_load_lds(
        (const __attribute__((address_space(1))) void*)g,
        (__attribute__((address_space(3))) void*)l, 16, 0, 0);
}

// ---------- weight transpose: WT[w][n][k] = f16(W[w][k][n]) ----------
__global__ __launch_bounds__(256) void transpose_w(
    const float* __restrict__ Wq, const float* __restrict__ Wk, const float* __restrict__ Wv,
    const float* __restrict__ Wg, const float* __restrict__ Wo, const float* __restrict__ W1,
    const float* __restrict__ W2, u16* __restrict__ WT)
{
    __shared__ float tile[64][65];
    const float* Ws[7] = {Wq, Wk, Wv, Wg, Wo, W1, W2};
    int w = blockIdx.z;
    int k0 = blockIdx.x * 64, n0 = blockIdx.y * 64;
    const float* W = Ws[w];
    int t = threadIdx.x;
    for (int c = t; c < 4096; c += 256) {
        int row = c >> 6, col = c & 63;
        tile[row][col] = W[(size_t)(k0 + row) * 512 + n0 + col];
    }
    __syncthreads();
    for (int c = t; c < 4096; c += 256) {
        int row = c >> 6, col = c & 63;
        WT[(size_t)w * 262144 + (size_t)(n0 + row) * 512 + k0 + col] = f2h(tile[col][row]);
    }
}

// ---------- LayerNorm; optional f32/f16 outputs; optional fused FC partial-dot ----------
// fcW mode: writes one plain float per block (fcpart[row]) — NO atomics (r10 lesson:
// 8192 same-line atomicAdds serialized to ~107 us).
__global__ __launch_bounds__(256) void ln_kernel(
    const float* __restrict__ xin,
    const int* __restrict__ ids, const float* __restrict__ emb, const float* __restrict__ pos,
    const float* __restrict__ gam, const float* __restrict__ bet,
    float* __restrict__ outf, u16* __restrict__ outh, int mode,
    const float* __restrict__ fcW, float* __restrict__ fcpart)
{
    __shared__ float red[8];
    __shared__ float red2[4];
    int row = blockIdx.x, t = threadIdx.x;
    int wid = t >> 6, lane = t & 63;
    float v0, v1;
    if (mode == 1) {
        int id = ids[2 * 8192 + row];
        const float* e = emb + (size_t)(2 * 1024 + id) * 512;
        const float* p = pos + (size_t)(2 * 1024 + (row & 1023)) * 512;
        v0 = e[t] + p[t];
        v1 = e[t + 256] + p[t + 256];
    } else {
        v0 = xin[(size_t)row * 512 + t];
        v1 = xin[(size_t)row * 512 + t + 256];
    }
    float s1 = v0 + v1, s2 = v0 * v0 + v1 * v1;
#pragma unroll
    for (int o = 32; o >= 1; o >>= 1) {
        s1 += __shfl_xor(s1, o, 64);
        s2 += __shfl_xor(s2, o, 64);
    }
    if (lane == 0) { red[wid] = s1; red[4 + wid] = s2; }
    __syncthreads();
    float S1 = red[0] + red[1] + red[2] + red[3];
    float S2 = red[4] + red[5] + red[6] + red[7];
    float mu = S1 * (1.f / 512.f);
    float var = fmaxf(S2 * (1.f / 512.f) - mu * mu, 0.f);
    float rs = 1.f / sqrtf(var + 1e-5f);
    float y0 = (v0 - mu) * rs * gam[t] + bet[t];
    float y1 = (v1 - mu) * rs * gam[t + 256] + bet[t + 256];
    if (outf) {
        outf[(size_t)row * 512 + t] = y0;
        outf[(size_t)row * 512 + t + 256] = y1;
    }
    if (outh) {
        outh[(size_t)row * 512 + t] = f2h(y0);
        outh[(size_t)row * 512 + t + 256] = f2h(y1);
    }
    if (fcW) {  // fused final FC partial: one plain store per block
        int srow = row & 1023;
        float d = y0 * fcW[(size_t)srow * 512 + t] + y1 * fcW[(size_t)srow * 512 + t + 256];
#pragma unroll
        for (int o = 32; o >= 1; o >>= 1) d += __shfl_xor(d, o, 64);
        if (lane == 0) red2[wid] = d;
        __syncthreads();
        if (t == 0) fcpart[row] = red2[0] + red2[1] + red2[2] + red2[3];
    }
}

// ---------- GEMM: C = A_f16 x B_f16^T ; global_load_lds staging, unpadded BK=32 LDS ----------
// mode 0: outf=C ; 1: outf=C+res ; 2: outh=f16(relu(C+bias)) ; 3: outf=C+bias+res ;
// 4: outh=f16(C) at ostride
__global__ __launch_bounds__(256) void gemm_f16(
    const u16* __restrict__ A2, const u16* __restrict__ Bg,
    float* __restrict__ outf, u16* __restrict__ outh,
    const float* __restrict__ res, const float* __restrict__ bias, int mode, int ostride)
{
    __shared__ u16 As[128 * 32];   // unpadded: matches global_load_lds lane*16B layout (m97)
    __shared__ u16 Bs[128 * 32];
    int t = threadIdx.x;
    int wid = t >> 6, lane = t & 63, quad = lane >> 4, l15 = lane & 15;
    int wm = wid >> 1, wn = wid & 1;
    int m0 = blockIdx.y * 128, n0 = blockIdx.x * 128;

    int srow = wid * 16 + (lane >> 2);
    int spart = (lane & 3) * 8;
    u16* ldsA0 = &As[(wid * 16) * 32];
    u16* ldsA1 = &As[(64 + wid * 16) * 32];
    u16* ldsB0 = &Bs[(wid * 16) * 32];
    u16* ldsB1 = &Bs[(64 + wid * 16) * 32];

    f32x4 acc[4][4];
#pragma unroll
    for (int a = 0; a < 4; ++a)
#pragma unroll
        for (int b = 0; b < 4; ++b) acc[a][b] = (f32x4){0.f, 0.f, 0.f, 0.f};

    for (int ki = 0; ki < 16; ++ki) {
        int k0 = ki * 32;
        __syncthreads();
        gl_lds16(&A2[(size_t)(m0 + srow) * 512 + k0 + spart], ldsA0);
        gl_lds16(&A2[(size_t)(m0 + 64 + srow) * 512 + k0 + spart], ldsA1);
        gl_lds16(&Bg[(size_t)(n0 + srow) * 512 + k0 + spart], ldsB0);
        gl_lds16(&Bg[(size_t)(n0 + 64 + srow) * 512 + k0 + spart], ldsB1);
        __syncthreads();
        half8 af[4], bf[4];
#pragma unroll
        for (int tm = 0; tm < 4; ++tm)
            af[tm] = *(const half8*)&As[(wm * 64 + tm * 16 + l15) * 32 + quad * 8];
#pragma unroll
        for (int tn = 0; tn < 4; ++tn)
            bf[tn] = *(const half8*)&Bs[(wn * 64 + tn * 16 + l15) * 32 + quad * 8];
#pragma unroll
        for (int tm = 0; tm < 4; ++tm)
#pragma unroll
            for (int tn = 0; tn < 4; ++tn)
                acc[tm][tn] = __builtin_amdgcn_mfma_f32_16x16x32_f16(af[tm], bf[tn], acc[tm][tn], 0, 0, 0);
    }

#pragma unroll
    for (int tm = 0; tm < 4; ++tm) {
#pragma unroll
        for (int tn = 0; tn < 4; ++tn) {
            int n = n0 + wn * 64 + tn * 16 + l15;
            int mbase = m0 + wm * 64 + tm * 16 + quad * 4;
#pragma unroll
            for (int r = 0; r < 4; ++r) {
                int m = mbase + r;
                float v = acc[tm][tn][r];
                if (mode == 1) v += res[(size_t)m * 512 + n];
                else if (mode == 2) v = fmaxf(v + bias[n], 0.f);
                else if (mode == 3) v += bias[n] + res[(size_t)m * 512 + n];
                if (mode == 2) outh[(size_t)m * 512 + n] = f2h(v);
                else if (mode == 4) outh[(size_t)m * ostride + n] = f2h(v);
                else outf[(size_t)m * ostride + n] = v;
            }
        }
    }
}

// ---------- fused retention, q-tile=128, m-tile=128 ----------
__global__ __launch_bounds__(256) void retention_f16(
    const u16* __restrict__ QKVGh, u16* __restrict__ Zh)
{
    __shared__ u16 kh[128 * 72];       // K tile [m][d], stride 72
    __shared__ u16 vth[64 * 144];      // V^T [d][m=128], stride 144, rotation-swizzled
    __shared__ u16 ph[4][32 * 136];    // per-wave P [qrow 32][m 128], stride 136

    int t = threadIdx.x;
    int wid = t >> 6, lane = t & 63, quad = lane >> 4, l15 = lane & 15;
    int bh = (blockIdx.x >> 3) & 63;
    int qtr = blockIdx.x & 7;
    int b = bh >> 3, h = bh & 7;
    int qt = ((blockIdx.x >> 8) & 1) ? (7 - qtr) : qtr;  // pairing balance
    int n0 = qt * 128;

    float gamma = 1.f - exp2f(-(float)(5 + h));
    float l2g = log2f(gamma);

    half8 aH[2][2];
#pragma unroll
    for (int g = 0; g < 2; ++g) {
        int qrow = b * 1024 + n0 + wid * 32 + g * 16 + l15;
        const u16* qp = QKVGh + (size_t)qrow * 2048 + h * 64;
#pragma unroll
        for (int ks = 0; ks < 2; ++ks)
            aH[g][ks] = *(const half8*)&qp[ks * 32 + quad * 8];
    }

    f32x4 yacc[2][4];
#pragma unroll
    for (int g = 0; g < 2; ++g)
#pragma unroll
        for (int dt = 0; dt < 4; ++dt) yacc[g][dt] = (f32x4){0.f, 0.f, 0.f, 0.f};

    for (int mt = 0; mt <= qt; ++mt) {
        __syncthreads();
        for (int c = t; c < 2048; c += 256) {
            int row = c >> 4, c4 = c & 15;
            size_t grow = (size_t)(b * 1024 + mt * 128 + row) * 2048;
            *(us4*)&kh[row * 72 + c4 * 4] = *(const us4*)&QKVGh[grow + 512 + h * 64 + c4 * 4];
        }
        for (int c = t; c < 2048; c += 256) {
            int d = c & 63, mseg = c >> 6;
            size_t gbase = (size_t)(b * 1024 + mt * 128 + mseg * 4) * 2048 + 1024 + h * 64 + d;
            us4 v4 = {QKVGh[gbase], QKVGh[gbase + 2048],
                      QKVGh[gbase + 4096], QKVGh[gbase + 6144]};
            int base = d * 144 + ((((mseg >> 1)) + d) & 15) * 8 + (mseg & 1) * 4;
            *(us4*)&vth[base] = v4;
        }
        __syncthreads();

#pragma unroll
        for (int g = 0; g < 2; ++g) {
            f32x4 sacc[8];
#pragma unroll
            for (int tn = 0; tn < 8; ++tn) sacc[tn] = (f32x4){0.f, 0.f, 0.f, 0.f};
#pragma unroll
            for (int tn = 0; tn < 8; ++tn)
#pragma unroll
                for (int ks = 0; ks < 2; ++ks) {
                    half8 bH = *(const half8*)&kh[(tn * 16 + l15) * 72 + ks * 32 + quad * 8];
                    sacc[tn] = __builtin_amdgcn_mfma_f32_16x16x32_f16(aH[g][ks], bH, sacc[tn], 0, 0, 0);
                }
#pragma unroll
            for (int tn = 0; tn < 8; ++tn) {
                int mglob = mt * 128 + tn * 16 + l15;
#pragma unroll
                for (int r = 0; r < 4; ++r) {
                    int nglob = n0 + wid * 32 + g * 16 + quad * 4 + r;
                    int diff = nglob - mglob;
                    float p = (diff >= 0) ? sacc[tn][r] * exp2f((float)diff * l2g - 3.0f) : 0.f;
                    ph[wid][(g * 16 + quad * 4 + r) * 136 + tn * 16 + l15] = f2h(p);
                }
            }
        }
#pragma unroll
        for (int g = 0; g < 2; ++g) {
            half8 pH[4];
#pragma unroll
            for (int ks = 0; ks < 4; ++ks)
                pH[ks] = *(const half8*)&ph[wid][(g * 16 + l15) * 136 + ks * 32 + quad * 8];
#pragma unroll
            for (int dt = 0; dt < 4; ++dt) {
                int d = dt * 16 + l15;
#pragma unroll
                for (int ks = 0; ks < 4; ++ks) {
                    half8 vv = *(const half8*)&vth[d * 144 + ((ks * 4 + quad + d) & 15) * 8];
                    yacc[g][dt] = __builtin_amdgcn_mfma_f32_16x16x32_f16(pH[ks], vv, yacc[g][dt], 0, 0, 0);
                }
            }
        }
    }

#pragma unroll
    for (int g = 0; g < 2; ++g) {
#pragma unroll
        for (int r = 0; r < 4; ++r) {
            float s1 = yacc[g][0][r] + yacc[g][1][r] + yacc[g][2][r] + yacc[g][3][r];
            float s2 = yacc[g][0][r] * yacc[g][0][r] + yacc[g][1][r] * yacc[g][1][r] +
                       yacc[g][2][r] * yacc[g][2][r] + yacc[g][3][r] * yacc[g][3][r];
#pragma unroll
            for (int o = 1; o <= 8; o <<= 1) {
                s1 += __shfl_xor(s1, o, 64);
                s2 += __shfl_xor(s2, o, 64);
            }
            float mu = s1 * (1.f / 64.f);
            float var = fmaxf(s2 * (1.f / 64.f) - mu * mu, 0.f);
            float rs = 1.f / sqrtf(var + 1e-5f);
            int nglob = n0 + wid * 32 + g * 16 + quad * 4 + r;
            size_t grow = (size_t)(b * 1024 + nglob);
#pragma unroll
            for (int dt = 0; dt < 4; ++dt) {
                int d = dt * 16 + l15;
                float yv = (yacc[g][dt][r] - mu) * rs;
                float gt = h2f(QKVGh[grow * 2048 + 1536 + h * 64 + d]);
                float sw = gt / (1.f + expf(-gt));
                Zh[grow * 512 + h * 64 + d] = f2h(yv * sw);
            }
        }
    }
}

// ---------- final reduce: logits[b] = sum of fcpart[b*1024 .. +1023]; sigmoid ----------
__global__ __launch_bounds__(256) void fc_final(const float* __restrict__ fcpart,
                                                const float* __restrict__ fcb,
                                                float* __restrict__ out)
{
    __shared__ float red[4];
    int b = blockIdx.x, t = threadIdx.x;
    float4 v = *(const float4*)&fcpart[(size_t)b * 1024 + t * 4];
    float s = v.x + v.y + v.z + v.w;
    int wid = t >> 6, lane = t & 63;
#pragma unroll
    for (int o = 32; o >= 1; o >>= 1) s += __shfl_xor(s, o, 64);
    if (lane == 0) red[wid] = s;
    __syncthreads();
    if (t == 0) {
        float l = red[0] + red[1] + red[2] + red[3] + fcb[0];
        out[b] = 1.f / (1.f + expf(-l));
    }
}

extern "C" void kernel_launch(void* const* d_in, const int* in_sizes, int n_in,
                              void* d_out, int out_size, void* d_ws, size_t ws_size,
                              hipStream_t stream)
{
    const int* ids = (const int*)d_in[0];
    const float* emb = (const float*)d_in[1];
    const float* pos = (const float*)d_in[2];
    const float* ln_g = (const float*)d_in[3];
    const float* ln_b = (const float*)d_in[4];
    const float* Wq = (const float*)d_in[5];
    const float* Wk = (const float*)d_in[6];
    const float* Wv = (const float*)d_in[7];
    const float* Wg = (const float*)d_in[8];
    const float* Wo = (const float*)d_in[9];
    const float* W1 = (const float*)d_in[10];
    const float* b1 = (const float*)d_in[11];
    const float* W2 = (const float*)d_in[12];
    const float* b2 = (const float*)d_in[13];
    const float* fcW = (const float*)d_in[14];
    const float* fcb = (const float*)d_in[15];
    float* out = (float*)d_out;

    char* ws = (char*)d_ws;
    u16* WT     = (u16*)(ws);                  //  3,670,016
    float* x0f  = (float*)(ws + 3670016);      // 16,777,216  LN(emb) f32 (residual)
    u16* x0h    = (u16*)(ws + 20447232);       //  8,388,608  LN(emb) f16
    u16* QKVGh  = (u16*)(ws + 28835840);       // 33,554,432  [8192][2048] f16
    float* fcpart = (float*)(ws + 62390272);   // 32,768  per-row FC partials
    u16* Zh   = x0h;                            // dead after QKVG GEMM
    float* X1 = (float*)QKVGh;                  // QKVGh dead after retention
    u16* Th   = (u16*)((char*)QKVGh + 16777216);
    u16* Hh   = (u16*)((char*)QKVGh + 25165824);
    float* X2 = x0f;                            // dead after Wo-GEMM residual

    // only vocab iteration i=2 is live (x overwritten each pass)
    transpose_w<<<dim3(8, 8, 7), 256, 0, stream>>>(Wq, Wk, Wv, Wg, Wo, W1, W2, WT);
    ln_kernel<<<8192, 256, 0, stream>>>(nullptr, ids, emb, pos, ln_g, ln_b, x0f, x0h, 1, nullptr, nullptr);
    gemm_f16<<<dim3(16, 64), 256, 0, stream>>>(x0h, WT, nullptr, QKVGh, nullptr, nullptr, 4, 2048);
    retention_f16<<<512, 256, 0, stream>>>(QKVGh, Zh);
    gemm_f16<<<dim3(4, 64), 256, 0, stream>>>(Zh, WT + 4 * 262144, X1, nullptr, x0f, nullptr, 1, 512);
    ln_kernel<<<8192, 256, 0, stream>>>(X1, nullptr, nullptr, nullptr, ln_g, ln_b, nullptr, Th, 0, nullptr, nullptr);
    gemm_f16<<<dim3(4, 64), 256, 0, stream>>>(Th, WT + 5 * 262144, nullptr, Hh, nullptr, b1, 2, 512);
    gemm_f16<<<dim3(4, 64), 256, 0, stream>>>(Hh, WT + 6 * 262144, X2, nullptr, X1, b2, 3, 512);
    // final LN fused with FC partial dot (plain per-block store, no atomics)
    ln_kernel<<<8192, 256, 0, stream>>>(X2, nullptr, nullptr, nullptr, ln_g, ln_b, nullptr, nullptr, 0, fcW, fcpart);
    fc_final<<<8, 256, 0, stream>>>(fcpart, fcb, out);
}

// Round 12
// 299.774 us; speedup vs baseline: 1.4593x; 1.1364x over previous
//
#include <hip/hip_runtime.h>
#include <math.h>

typedef unsigned short u16;
typedef __attribute__((ext_vector_type(8))) _Float16 half8;
typedef __attribute__((ext_vector_type(4))) float f32x4;
typedef __attribute__((ext_vector_type(4))) unsigned short us4;

// Inputs f32, output f32 (proven r4-11). All inter-kernel activations f16.

static __device__ __forceinline__ u16 f2h(float f) {
    _Float16 h = (_Float16)f;
    return __builtin_bit_cast(u16, h);
}
static __device__ __forceinline__ float h2f(u16 u) {
    return (float)__builtin_bit_cast(_Float16, u);
}
// async global->LDS DMA, 16B/lane; lds base wave-uniform (HW adds lane*16)
static __device__ __forceinline__ void gl_lds16(const void* g, void* l) {
    __builtin_amdgcn_global_load_lds(
        (const __attribute__((address_space(1))) void*)g,
        (__attribute__((address_space(3))) void*)l, 16, 0, 0);
}

// ---------- weight transpose: WT[w][n][k] = f16(W[w][k][n]) ----------
__global__ __launch_bounds__(256) void transpose_w(
    const float* __restrict__ Wq, const float* __restrict__ Wk, const float* __restrict__ Wv,
    const float* __restrict__ Wg, const float* __restrict__ Wo, const float* __restrict__ W1,
    const float* __restrict__ W2, u16* __restrict__ WT)
{
    __shared__ float tile[64][65];
    const float* Ws[7] = {Wq, Wk, Wv, Wg, Wo, W1, W2};
    int w = blockIdx.z;
    int k0 = blockIdx.x * 64, n0 = blockIdx.y * 64;
    const float* W = Ws[w];
    int t = threadIdx.x;
    for (int c = t; c < 4096; c += 256) {
        int row = c >> 6, col = c & 63;
        tile[row][col] = W[(size_t)(k0 + row) * 512 + n0 + col];
    }
    __syncthreads();
    for (int c = t; c < 4096; c += 256) {
        int row = c >> 6, col = c & 63;
        WT[(size_t)w * 262144 + (size_t)(n0 + row) * 512 + k0 + col] = f2h(tile[col][row]);
    }
}

// ---------- LayerNorm: f16 in (or fused embed gather), f16 out; optional FC partial ----------
__global__ __launch_bounds__(256) void ln_kernel(
    const u16* __restrict__ xin,
    const int* __restrict__ ids, const float* __restrict__ emb, const float* __restrict__ pos,
    const float* __restrict__ gam, const float* __restrict__ bet,
    u16* __restrict__ outh, int mode,
    const float* __restrict__ fcW, float* __restrict__ fcpart)
{
    __shared__ float red[8];
    __shared__ float red2[4];
    int row = blockIdx.x, t = threadIdx.x;
    int wid = t >> 6, lane = t & 63;
    float v0, v1;
    if (mode == 1) {
        int id = ids[2 * 8192 + row];
        const float* e = emb + (size_t)(2 * 1024 + id) * 512;
        const float* p = pos + (size_t)(2 * 1024 + (row & 1023)) * 512;
        v0 = e[t] + p[t];
        v1 = e[t + 256] + p[t + 256];
    } else {
        v0 = h2f(xin[(size_t)row * 512 + t]);
        v1 = h2f(xin[(size_t)row * 512 + t + 256]);
    }
    float s1 = v0 + v1, s2 = v0 * v0 + v1 * v1;
#pragma unroll
    for (int o = 32; o >= 1; o >>= 1) {
        s1 += __shfl_xor(s1, o, 64);
        s2 += __shfl_xor(s2, o, 64);
    }
    if (lane == 0) { red[wid] = s1; red[4 + wid] = s2; }
    __syncthreads();
    float S1 = red[0] + red[1] + red[2] + red[3];
    float S2 = red[4] + red[5] + red[6] + red[7];
    float mu = S1 * (1.f / 512.f);
    float var = fmaxf(S2 * (1.f / 512.f) - mu * mu, 0.f);
    float rs = 1.f / sqrtf(var + 1e-5f);
    float y0 = (v0 - mu) * rs * gam[t] + bet[t];
    float y1 = (v1 - mu) * rs * gam[t + 256] + bet[t + 256];
    if (outh) {
        outh[(size_t)row * 512 + t] = f2h(y0);
        outh[(size_t)row * 512 + t + 256] = f2h(y1);
    }
    if (fcW) {  // fused final FC partial: one plain store per block (no atomics — r10 lesson)
        int srow = row & 1023;
        float d = y0 * fcW[(size_t)srow * 512 + t] + y1 * fcW[(size_t)srow * 512 + t + 256];
#pragma unroll
        for (int o = 32; o >= 1; o >>= 1) d += __shfl_xor(d, o, 64);
        if (lane == 0) red2[wid] = d;
        __syncthreads();
        if (t == 0) fcpart[row] = red2[0] + red2[1] + red2[2] + red2[3];
    }
}

// ---------- GEMM: outh = f16(A_f16 x B_f16^T [+ eps]) ; gl_lds staging, BK=32 ----------
// mode 0: C ; 1: C+res16 ; 2: relu(C+bias) ; 3: C+bias+res16
__global__ __launch_bounds__(256) void gemm_f16(
    const u16* __restrict__ A2, const u16* __restrict__ Bg,
    u16* __restrict__ outh,
    const u16* __restrict__ res, const float* __restrict__ bias, int mode, int ostride)
{
    __shared__ u16 As[128 * 32];   // unpadded: matches global_load_lds lane*16B layout (m97)
    __shared__ u16 Bs[128 * 32];
    int t = threadIdx.x;
    int wid = t >> 6, lane = t & 63, quad = lane >> 4, l15 = lane & 15;
    int wm = wid >> 1, wn = wid & 1;
    int m0 = blockIdx.y * 128, n0 = blockIdx.x * 128;

    int srow = wid * 16 + (lane >> 2);
    int spart = (lane & 3) * 8;
    u16* ldsA0 = &As[(wid * 16) * 32];
    u16* ldsA1 = &As[(64 + wid * 16) * 32];
    u16* ldsB0 = &Bs[(wid * 16) * 32];
    u16* ldsB1 = &Bs[(64 + wid * 16) * 32];

    f32x4 acc[4][4];
#pragma unroll
    for (int a = 0; a < 4; ++a)
#pragma unroll
        for (int b = 0; b < 4; ++b) acc[a][b] = (f32x4){0.f, 0.f, 0.f, 0.f};

    for (int ki = 0; ki < 16; ++ki) {
        int k0 = ki * 32;
        __syncthreads();
        gl_lds16(&A2[(size_t)(m0 + srow) * 512 + k0 + spart], ldsA0);
        gl_lds16(&A2[(size_t)(m0 + 64 + srow) * 512 + k0 + spart], ldsA1);
        gl_lds16(&Bg[(size_t)(n0 + srow) * 512 + k0 + spart], ldsB0);
        gl_lds16(&Bg[(size_t)(n0 + 64 + srow) * 512 + k0 + spart], ldsB1);
        __syncthreads();
        half8 af[4], bf[4];
#pragma unroll
        for (int tm = 0; tm < 4; ++tm)
            af[tm] = *(const half8*)&As[(wm * 64 + tm * 16 + l15) * 32 + quad * 8];
#pragma unroll
        for (int tn = 0; tn < 4; ++tn)
            bf[tn] = *(const half8*)&Bs[(wn * 64 + tn * 16 + l15) * 32 + quad * 8];
#pragma unroll
        for (int tm = 0; tm < 4; ++tm)
#pragma unroll
            for (int tn = 0; tn < 4; ++tn)
                acc[tm][tn] = __builtin_amdgcn_mfma_f32_16x16x32_f16(af[tm], bf[tn], acc[tm][tn], 0, 0, 0);
    }

#pragma unroll
    for (int tm = 0; tm < 4; ++tm) {
#pragma unroll
        for (int tn = 0; tn < 4; ++tn) {
            int n = n0 + wn * 64 + tn * 16 + l15;
            int mbase = m0 + wm * 64 + tm * 16 + quad * 4;
#pragma unroll
            for (int r = 0; r < 4; ++r) {
                int m = mbase + r;
                float v = acc[tm][tn][r];
                if (mode == 1) v += h2f(res[(size_t)m * 512 + n]);
                else if (mode == 2) v = fmaxf(v + bias[n], 0.f);
                else if (mode == 3) v += bias[n] + h2f(res[(size_t)m * 512 + n]);
                outh[(size_t)m * ostride + n] = f2h(v);
            }
        }
    }
}

// ---------- fused retention, q-tile=128, m-tile=128; reg-prefetch pipeline ----------
// LDS 53.8 KB -> 3 blocks/CU (r11 was 71.7 KB -> 2): per-group P buffer, stride 132.
__global__ __launch_bounds__(256) void retention_f16(
    const u16* __restrict__ QKVGh, u16* __restrict__ Zh)
{
    __shared__ u16 kh[128 * 72];       // K tile [m][d], stride 72
    __shared__ u16 vth[64 * 144];      // V^T [d][m=128], stride 144, rotation-swizzled
    __shared__ u16 ph[4][16 * 132];    // per-wave per-group P [16 qrow][128 m], stride 132

    int t = threadIdx.x;
    int wid = t >> 6, lane = t & 63, quad = lane >> 4, l15 = lane & 15;
    int bh = (blockIdx.x >> 3) & 63;
    int qtr = blockIdx.x & 7;
    int b = bh >> 3, h = bh & 7;
    int qt = ((blockIdx.x >> 8) & 1) ? (7 - qtr) : qtr;  // pairing balance
    int n0 = qt * 128;

    float gamma = 1.f - exp2f(-(float)(5 + h));
    float l2g = log2f(gamma);

    half8 aH[2][2];
#pragma unroll
    for (int g = 0; g < 2; ++g) {
        int qrow = b * 1024 + n0 + wid * 32 + g * 16 + l15;
        const u16* qp = QKVGh + (size_t)qrow * 2048 + h * 64;
#pragma unroll
        for (int ks = 0; ks < 2; ++ks)
            aH[g][ks] = *(const half8*)&qp[ks * 32 + quad * 8];
    }

    f32x4 yacc[2][4];
#pragma unroll
    for (int g = 0; g < 2; ++g)
#pragma unroll
        for (int dt = 0; dt < 4; ++dt) yacc[g][dt] = (f32x4){0.f, 0.f, 0.f, 0.f};

    // register prefetch buffers: K 8 x us4, V 8 x us4 (~32 VGPRs)
    us4 kreg[8], vreg[8];
#pragma unroll
    for (int i = 0; i < 8; ++i) {  // preload tile 0
        int c = t + i * 256;
        int row = c >> 4, c4 = c & 15;
        kreg[i] = *(const us4*)&QKVGh[(size_t)(b * 1024 + row) * 2048 + 512 + h * 64 + c4 * 4];
        int d = c & 63, mseg = c >> 6;
        size_t gbase = (size_t)(b * 1024 + mseg * 4) * 2048 + 1024 + h * 64 + d;
        vreg[i] = (us4){QKVGh[gbase], QKVGh[gbase + 2048],
                        QKVGh[gbase + 4096], QKVGh[gbase + 6144]};
    }

    for (int mt = 0; mt <= qt; ++mt) {
        __syncthreads();
        // store prefetched tile to LDS
#pragma unroll
        for (int i = 0; i < 8; ++i) {
            int c = t + i * 256;
            int row = c >> 4, c4 = c & 15;
            *(us4*)&kh[row * 72 + c4 * 4] = kreg[i];
            int d = c & 63, mseg = c >> 6;
            int base = d * 144 + (((mseg >> 1) + d) & 15) * 8 + (mseg & 1) * 4;
            *(us4*)&vth[base] = vreg[i];
        }
        __syncthreads();
        // issue next-tile loads now; latency overlaps the MFMA section below
        if (mt < qt) {
#pragma unroll
            for (int i = 0; i < 8; ++i) {
                int c = t + i * 256;
                int row = c >> 4, c4 = c & 15;
                kreg[i] = *(const us4*)&QKVGh[(size_t)(b * 1024 + (mt + 1) * 128 + row) * 2048 + 512 + h * 64 + c4 * 4];
                int d = c & 63, mseg = c >> 6;
                size_t gbase = (size_t)(b * 1024 + (mt + 1) * 128 + mseg * 4) * 2048 + 1024 + h * 64 + d;
                vreg[i] = (us4){QKVGh[gbase], QKVGh[gbase + 2048],
                                QKVGh[gbase + 4096], QKVGh[gbase + 6144]};
            }
        }

#pragma unroll
        for (int g = 0; g < 2; ++g) {
            f32x4 sacc[8];
#pragma unroll
            for (int tn = 0; tn < 8; ++tn) sacc[tn] = (f32x4){0.f, 0.f, 0.f, 0.f};
#pragma unroll
            for (int tn = 0; tn < 8; ++tn)
#pragma unroll
                for (int ks = 0; ks < 2; ++ks) {
                    half8 bH = *(const half8*)&kh[(tn * 16 + l15) * 72 + ks * 32 + quad * 8];
                    sacc[tn] = __builtin_amdgcn_mfma_f32_16x16x32_f16(aH[g][ks], bH, sacc[tn], 0, 0, 0);
                }
#pragma unroll
            for (int tn = 0; tn < 8; ++tn) {
                int mglob = mt * 128 + tn * 16 + l15;                 // D col
#pragma unroll
                for (int r = 0; r < 4; ++r) {
                    int nglob = n0 + wid * 32 + g * 16 + quad * 4 + r;  // D row
                    int diff = nglob - mglob;
                    float p = (diff >= 0) ? sacc[tn][r] * exp2f((float)diff * l2g - 3.0f) : 0.f;
                    ph[wid][(quad * 4 + r) * 132 + tn * 16 + l15] = f2h(p);
                }
            }
            // PV for this group (per-wave P; within-wave DS ordering, no barrier)
            half8 pH[4];
#pragma unroll
            for (int ks = 0; ks < 4; ++ks)
                pH[ks] = *(const half8*)&ph[wid][l15 * 132 + ks * 32 + quad * 8];
#pragma unroll
            for (int dt = 0; dt < 4; ++dt) {
                int d = dt * 16 + l15;
#pragma unroll
                for (int ks = 0; ks < 4; ++ks) {
                    half8 vv = *(const half8*)&vth[d * 144 + ((ks * 4 + quad + d) & 15) * 8];
                    yacc[g][dt] = __builtin_amdgcn_mfma_f32_16x16x32_f16(pH[ks], vv, yacc[g][dt], 0, 0, 0);
                }
            }
        }
    }

#pragma unroll
    for (int g = 0; g < 2; ++g) {
#pragma unroll
        for (int r = 0; r < 4; ++r) {
            float s1 = yacc[g][0][r] + yacc[g][1][r] + yacc[g][2][r] + yacc[g][3][r];
            float s2 = yacc[g][0][r] * yacc[g][0][r] + yacc[g][1][r] * yacc[g][1][r] +
                       yacc[g][2][r] * yacc[g][2][r] + yacc[g][3][r] * yacc[g][3][r];
#pragma unroll
            for (int o = 1; o <= 8; o <<= 1) {
                s1 += __shfl_xor(s1, o, 64);
                s2 += __shfl_xor(s2, o, 64);
            }
            float mu = s1 * (1.f / 64.f);
            float var = fmaxf(s2 * (1.f / 64.f) - mu * mu, 0.f);
            float rs = 1.f / sqrtf(var + 1e-5f);
            int nglob = n0 + wid * 32 + g * 16 + quad * 4 + r;
            size_t grow = (size_t)(b * 1024 + nglob);
#pragma unroll
            for (int dt = 0; dt < 4; ++dt) {
                int d = dt * 16 + l15;
                float yv = (yacc[g][dt][r] - mu) * rs;
                float gt = h2f(QKVGh[grow * 2048 + 1536 + h * 64 + d]);
                float sw = gt / (1.f + expf(-gt));
                Zh[grow * 512 + h * 64 + d] = f2h(yv * sw);
            }
        }
    }
}

// ---------- final reduce: logits[b] = sum fcpart[b*1024..]; sigmoid ----------
__global__ __launch_bounds__(256) void fc_final(const float* __restrict__ fcpart,
                                                const float* __restrict__ fcb,
                                                float* __restrict__ out)
{
    __shared__ float red[4];
    int b = blockIdx.x, t = threadIdx.x;
    float4 v = *(const float4*)&fcpart[(size_t)b * 1024 + t * 4];
    float s = v.x + v.y + v.z + v.w;
    int wid = t >> 6, lane = t & 63;
#pragma unroll
    for (int o = 32; o >= 1; o >>= 1) s += __shfl_xor(s, o, 64);
    if (lane == 0) red[wid] = s;
    __syncthreads();
    if (t == 0) {
        float l = red[0] + red[1] + red[2] + red[3] + fcb[0];
        out[b] = 1.f / (1.f + expf(-l));
    }
}

extern "C" void kernel_launch(void* const* d_in, const int* in_sizes, int n_in,
                              void* d_out, int out_size, void* d_ws, size_t ws_size,
                              hipStream_t stream)
{
    const int* ids = (const int*)d_in[0];
    const float* emb = (const float*)d_in[1];
    const float* pos = (const float*)d_in[2];
    const float* ln_g = (const float*)d_in[3];
    const float* ln_b = (const float*)d_in[4];
    const float* Wq = (const float*)d_in[5];
    const float* Wk = (const float*)d_in[6];
    const float* Wv = (const float*)d_in[7];
    const float* Wg = (const float*)d_in[8];
    const float* Wo = (const float*)d_in[9];
    const float* W1 = (const float*)d_in[10];
    const float* b1 = (const float*)d_in[11];
    const float* W2 = (const float*)d_in[12];
    const float* b2 = (const float*)d_in[13];
    const float* fcW = (const float*)d_in[14];
    const float* fcb = (const float*)d_in[15];
    float* out = (float*)d_out;

    char* ws = (char*)d_ws;
    u16* WT     = (u16*)(ws);                  //  3,670,016
    u16* x0h    = (u16*)(ws + 3670016);        //  8,388,608  LN(emb) f16 (A + residual)
    u16* Zh     = (u16*)(ws + 12058624);       //  8,388,608  retention out f16
    u16* QKVGh  = (u16*)(ws + 20447232);       // 33,554,432  [8192][2048] f16
    float* fcpart = (float*)(ws + 54001664);   // 32,768
    // QKVGh region reused after retention:
    u16* X1h = QKVGh;                           // Wo out (residual for W2)
    u16* Th  = (u16*)((char*)QKVGh + 8388608);  // ln2 out
    u16* Hh  = (u16*)((char*)QKVGh + 16777216); // W1 out
    u16* X2h = Zh;                              // Zh dead after Wo-GEMM

    // only vocab iteration i=2 is live (x overwritten each pass)
    transpose_w<<<dim3(8, 8, 7), 256, 0, stream>>>(Wq, Wk, Wv, Wg, Wo, W1, W2, WT);
    ln_kernel<<<8192, 256, 0, stream>>>(nullptr, ids, emb, pos, ln_g, ln_b, x0h, 1, nullptr, nullptr);
    gemm_f16<<<dim3(16, 64), 256, 0, stream>>>(x0h, WT, QKVGh, nullptr, nullptr, 0, 2048);
    retention_f16<<<512, 256, 0, stream>>>(QKVGh, Zh);
    gemm_f16<<<dim3(4, 64), 256, 0, stream>>>(Zh, WT + 4 * 262144, X1h, x0h, nullptr, 1, 512);
    ln_kernel<<<8192, 256, 0, stream>>>(X1h, nullptr, nullptr, nullptr, ln_g, ln_b, Th, 0, nullptr, nullptr);
    gemm_f16<<<dim3(4, 64), 256, 0, stream>>>(Th, WT + 5 * 262144, Hh, nullptr, b1, 2, 512);
    gemm_f16<<<dim3(4, 64), 256, 0, stream>>>(Hh, WT + 6 * 262144, X2h, X1h, b2, 3, 512);
    // final LN fused with FC partial dot (plain per-block store)
    ln_kernel<<<8192, 256, 0, stream>>>(X2h, nullptr, nullptr, nullptr, ln_g, ln_b, nullptr, 0, fcW, fcpart);
    fc_final<<<8, 256, 0, stream>>>(fcpart, fcb, out);
}

// Round 13
// 278.314 us; speedup vs baseline: 1.5718x; 1.0771x over previous
//
#include <hip/hip_runtime.h>
#include <math.h>

typedef unsigned short u16;
typedef __attribute__((ext_vector_type(8))) _Float16 half8;
typedef __attribute__((ext_vector_type(4))) float f32x4;
typedef __attribute__((ext_vector_type(4))) unsigned short us4;

// Inputs f32, output f32 (proven r4-12). All inter-kernel activations f16.

static __device__ __forceinline__ u16 f2h(float f) {
    _Float16 h = (_Float16)f;
    return __builtin_bit_cast(u16, h);
}
static __device__ __forceinline__ float h2f(u16 u) {
    return (float)__builtin_bit_cast(_Float16, u);
}
// async global->LDS DMA, 16B/lane; lds base wave-uniform (HW adds lane*16)
static __device__ __forceinline__ void gl_lds16(const void* g, void* l) {
    __builtin_amdgcn_global_load_lds(
        (const __attribute__((address_space(1))) void*)g,
        (__attribute__((address_space(3))) void*)l, 16, 0, 0);
}

// ---------- weight transpose: WT[w][n][k] = f16(W[w][k][n]) ----------
__global__ __launch_bounds__(256) void transpose_w(
    const float* __restrict__ Wq, const float* __restrict__ Wk, const float* __restrict__ Wv,
    const float* __restrict__ Wg, const float* __restrict__ Wo, const float* __restrict__ W1,
    const float* __restrict__ W2, u16* __restrict__ WT)
{
    __shared__ float tile[64][65];
    const float* Ws[7] = {Wq, Wk, Wv, Wg, Wo, W1, W2};
    int w = blockIdx.z;
    int k0 = blockIdx.x * 64, n0 = blockIdx.y * 64;
    const float* W = Ws[w];
    int t = threadIdx.x;
    for (int c = t; c < 4096; c += 256) {
        int row = c >> 6, col = c & 63;
        tile[row][col] = W[(size_t)(k0 + row) * 512 + n0 + col];
    }
    __syncthreads();
    for (int c = t; c < 4096; c += 256) {
        int row = c >> 6, col = c & 63;
        WT[(size_t)w * 262144 + (size_t)(n0 + row) * 512 + k0 + col] = f2h(tile[col][row]);
    }
}

// ---------- LayerNorm, row-per-wave (4 rows/block, no LDS, no barriers) ----------
// mode 1: fused embedding gather (vocab slice 2). Optional fused FC partial dot.
__global__ __launch_bounds__(256) void ln_kernel(
    const u16* __restrict__ xin,
    const int* __restrict__ ids, const float* __restrict__ emb, const float* __restrict__ pos,
    const float* __restrict__ gam, const float* __restrict__ bet,
    u16* __restrict__ outh, int mode,
    const float* __restrict__ fcW, float* __restrict__ fcpart)
{
    int wid = threadIdx.x >> 6, lane = threadIdx.x & 63;
    int row = blockIdx.x * 4 + wid;
    int col = lane * 8;
    float v[8];
    if (mode == 1) {
        int id = ids[2 * 8192 + row];
        const float* e = emb + (size_t)(2 * 1024 + id) * 512 + col;
        const float* p = pos + (size_t)(2 * 1024 + (row & 1023)) * 512 + col;
        float4 e0 = *(const float4*)e, e1 = *(const float4*)(e + 4);
        float4 p0 = *(const float4*)p, p1 = *(const float4*)(p + 4);
        v[0] = e0.x + p0.x; v[1] = e0.y + p0.y; v[2] = e0.z + p0.z; v[3] = e0.w + p0.w;
        v[4] = e1.x + p1.x; v[5] = e1.y + p1.y; v[6] = e1.z + p1.z; v[7] = e1.w + p1.w;
    } else {
        half8 x = *(const half8*)&xin[(size_t)row * 512 + col];
#pragma unroll
        for (int j = 0; j < 8; ++j) v[j] = (float)x[j];
    }
    float s1 = 0.f, s2 = 0.f;
#pragma unroll
    for (int j = 0; j < 8; ++j) { s1 += v[j]; s2 += v[j] * v[j]; }
#pragma unroll
    for (int o = 32; o >= 1; o >>= 1) {
        s1 += __shfl_xor(s1, o, 64);
        s2 += __shfl_xor(s2, o, 64);
    }
    float mu = s1 * (1.f / 512.f);
    float var = fmaxf(s2 * (1.f / 512.f) - mu * mu, 0.f);
    float rs = 1.f / sqrtf(var + 1e-5f);
    float4 g0 = *(const float4*)&gam[col], g1 = *(const float4*)&gam[col + 4];
    float4 b0 = *(const float4*)&bet[col], b1 = *(const float4*)&bet[col + 4];
    float gv[8] = {g0.x, g0.y, g0.z, g0.w, g1.x, g1.y, g1.z, g1.w};
    float bv[8] = {b0.x, b0.y, b0.z, b0.w, b1.x, b1.y, b1.z, b1.w};
    float y[8];
#pragma unroll
    for (int j = 0; j < 8; ++j) y[j] = (v[j] - mu) * rs * gv[j] + bv[j];
    if (outh) {
        half8 hv;
#pragma unroll
        for (int j = 0; j < 8; ++j) hv[j] = (_Float16)y[j];
        *(half8*)&outh[(size_t)row * 512 + col] = hv;
    }
    if (fcW) {  // fused final FC partial: plain store (no atomics — r10 lesson)
        int srow = row & 1023;
        const float* wp = &fcW[(size_t)srow * 512 + col];
        float4 w0 = *(const float4*)wp, w1 = *(const float4*)(wp + 4);
        float d = y[0] * w0.x + y[1] * w0.y + y[2] * w0.z + y[3] * w0.w +
                  y[4] * w1.x + y[5] * w1.y + y[6] * w1.z + y[7] * w1.w;
#pragma unroll
        for (int o = 32; o >= 1; o >>= 1) d += __shfl_xor(d, o, 64);
        if (lane == 0) fcpart[row] = d;
    }
}

// ---------- GEMM: outh = f16(A_f16 x B_f16^T [+ eps]); gl_lds staging, BK=64 ----------
// 8 k-iters (halved barrier count vs BK=32). LDS 32 KB -> 4-5 blocks/CU.
// mode 0: C ; 1: C+res16 ; 2: relu(C+bias) ; 3: C+bias+res16
__global__ __launch_bounds__(256) void gemm_f16(
    const u16* __restrict__ A2, const u16* __restrict__ Bg,
    u16* __restrict__ outh,
    const u16* __restrict__ res, const float* __restrict__ bias, int mode, int ostride)
{
    __shared__ u16 As[128 * 64];   // packed [row][k], stride 64 (m97 pattern)
    __shared__ u16 Bs[128 * 64];
    int t = threadIdx.x;
    int wid = t >> 6, lane = t & 63, quad = lane >> 4, l15 = lane & 15;
    int wm = wid >> 1, wn = wid & 1;
    int m0 = blockIdx.y * 128, n0 = blockIdx.x * 128;

    // staging: issue i covers rows i*32 + wid*8 .. +7; lane -> (row += lane>>3, col (lane&7)*8)
    int srow = wid * 8 + (lane >> 3);
    int scol = (lane & 7) * 8;

    f32x4 acc[4][4];
#pragma unroll
    for (int a = 0; a < 4; ++a)
#pragma unroll
        for (int b = 0; b < 4; ++b) acc[a][b] = (f32x4){0.f, 0.f, 0.f, 0.f};

    for (int ki = 0; ki < 8; ++ki) {
        int k0 = ki * 64;
        __syncthreads();
#pragma unroll
        for (int i = 0; i < 4; ++i) {
            int r = i * 32 + srow;
            gl_lds16(&A2[(size_t)(m0 + r) * 512 + k0 + scol], &As[(i * 32 + wid * 8) * 64]);
            gl_lds16(&Bg[(size_t)(n0 + r) * 512 + k0 + scol], &Bs[(i * 32 + wid * 8) * 64]);
        }
        __syncthreads();
#pragma unroll
        for (int ks = 0; ks < 2; ++ks) {
            half8 af[4], bf[4];
#pragma unroll
            for (int tm = 0; tm < 4; ++tm)
                af[tm] = *(const half8*)&As[(wm * 64 + tm * 16 + l15) * 64 + ks * 32 + quad * 8];
#pragma unroll
            for (int tn = 0; tn < 4; ++tn)
                bf[tn] = *(const half8*)&Bs[(wn * 64 + tn * 16 + l15) * 64 + ks * 32 + quad * 8];
#pragma unroll
            for (int tm = 0; tm < 4; ++tm)
#pragma unroll
                for (int tn = 0; tn < 4; ++tn)
                    acc[tm][tn] = __builtin_amdgcn_mfma_f32_16x16x32_f16(af[tm], bf[tn], acc[tm][tn], 0, 0, 0);
        }
    }

#pragma unroll
    for (int tm = 0; tm < 4; ++tm) {
#pragma unroll
        for (int tn = 0; tn < 4; ++tn) {
            int n = n0 + wn * 64 + tn * 16 + l15;
            int mbase = m0 + wm * 64 + tm * 16 + quad * 4;
#pragma unroll
            for (int r = 0; r < 4; ++r) {
                int m = mbase + r;
                float v = acc[tm][tn][r];
                if (mode == 1) v += h2f(res[(size_t)m * 512 + n]);
                else if (mode == 2) v = fmaxf(v + bias[n], 0.f);
                else if (mode == 3) v += bias[n] + h2f(res[(size_t)m * 512 + n]);
                outh[(size_t)m * ostride + n] = f2h(v);
            }
        }
    }
}

// ---------- fused retention, q-tile=128, m-tile=128; reg-prefetch pipeline (r12) ----------
__global__ __launch_bounds__(256) void retention_f16(
    const u16* __restrict__ QKVGh, u16* __restrict__ Zh)
{
    __shared__ u16 kh[128 * 72];       // K tile [m][d], stride 72
    __shared__ u16 vth[64 * 144];      // V^T [d][m=128], stride 144, rotation-swizzled
    __shared__ u16 ph[4][16 * 132];    // per-wave per-group P [16 qrow][128 m], stride 132

    int t = threadIdx.x;
    int wid = t >> 6, lane = t & 63, quad = lane >> 4, l15 = lane & 15;
    int bh = (blockIdx.x >> 3) & 63;
    int qtr = blockIdx.x & 7;
    int b = bh >> 3, h = bh & 7;
    int qt = ((blockIdx.x >> 8) & 1) ? (7 - qtr) : qtr;  // pairing balance
    int n0 = qt * 128;

    float gamma = 1.f - exp2f(-(float)(5 + h));
    float l2g = log2f(gamma);

    half8 aH[2][2];
#pragma unroll
    for (int g = 0; g < 2; ++g) {
        int qrow = b * 1024 + n0 + wid * 32 + g * 16 + l15;
        const u16* qp = QKVGh + (size_t)qrow * 2048 + h * 64;
#pragma unroll
        for (int ks = 0; ks < 2; ++ks)
            aH[g][ks] = *(const half8*)&qp[ks * 32 + quad * 8];
    }

    f32x4 yacc[2][4];
#pragma unroll
    for (int g = 0; g < 2; ++g)
#pragma unroll
        for (int dt = 0; dt < 4; ++dt) yacc[g][dt] = (f32x4){0.f, 0.f, 0.f, 0.f};

    us4 kreg[8], vreg[8];
#pragma unroll
    for (int i = 0; i < 8; ++i) {  // preload tile 0
        int c = t + i * 256;
        int row = c >> 4, c4 = c & 15;
        kreg[i] = *(const us4*)&QKVGh[(size_t)(b * 1024 + row) * 2048 + 512 + h * 64 + c4 * 4];
        int d = c & 63, mseg = c >> 6;
        size_t gbase = (size_t)(b * 1024 + mseg * 4) * 2048 + 1024 + h * 64 + d;
        vreg[i] = (us4){QKVGh[gbase], QKVGh[gbase + 2048],
                        QKVGh[gbase + 4096], QKVGh[gbase + 6144]};
    }

    for (int mt = 0; mt <= qt; ++mt) {
        __syncthreads();
#pragma unroll
        for (int i = 0; i < 8; ++i) {
            int c = t + i * 256;
            int row = c >> 4, c4 = c & 15;
            *(us4*)&kh[row * 72 + c4 * 4] = kreg[i];
            int d = c & 63, mseg = c >> 6;
            int base = d * 144 + (((mseg >> 1) + d) & 15) * 8 + (mseg & 1) * 4;
            *(us4*)&vth[base] = vreg[i];
        }
        __syncthreads();
        if (mt < qt) {  // issue next-tile loads; latency overlaps MFMA below
#pragma unroll
            for (int i = 0; i < 8; ++i) {
                int c = t + i * 256;
                int row = c >> 4, c4 = c & 15;
                kreg[i] = *(const us4*)&QKVGh[(size_t)(b * 1024 + (mt + 1) * 128 + row) * 2048 + 512 + h * 64 + c4 * 4];
                int d = c & 63, mseg = c >> 6;
                size_t gbase = (size_t)(b * 1024 + (mt + 1) * 128 + mseg * 4) * 2048 + 1024 + h * 64 + d;
                vreg[i] = (us4){QKVGh[gbase], QKVGh[gbase + 2048],
                                QKVGh[gbase + 4096], QKVGh[gbase + 6144]};
            }
        }

#pragma unroll
        for (int g = 0; g < 2; ++g) {
            f32x4 sacc[8];
#pragma unroll
            for (int tn = 0; tn < 8; ++tn) sacc[tn] = (f32x4){0.f, 0.f, 0.f, 0.f};
#pragma unroll
            for (int tn = 0; tn < 8; ++tn)
#pragma unroll
                for (int ks = 0; ks < 2; ++ks) {
                    half8 bH = *(const half8*)&kh[(tn * 16 + l15) * 72 + ks * 32 + quad * 8];
                    sacc[tn] = __builtin_amdgcn_mfma_f32_16x16x32_f16(aH[g][ks], bH, sacc[tn], 0, 0, 0);
                }
#pragma unroll
            for (int tn = 0; tn < 8; ++tn) {
                int mglob = mt * 128 + tn * 16 + l15;
#pragma unroll
                for (int r = 0; r < 4; ++r) {
                    int nglob = n0 + wid * 32 + g * 16 + quad * 4 + r;
                    int diff = nglob - mglob;
                    float p = (diff >= 0) ? sacc[tn][r] * exp2f((float)diff * l2g - 3.0f) : 0.f;
                    ph[wid][(quad * 4 + r) * 132 + tn * 16 + l15] = f2h(p);
                }
            }
            half8 pH[4];
#pragma unroll
            for (int ks = 0; ks < 4; ++ks)
                pH[ks] = *(const half8*)&ph[wid][l15 * 132 + ks * 32 + quad * 8];
#pragma unroll
            for (int dt = 0; dt < 4; ++dt) {
                int d = dt * 16 + l15;
#pragma unroll
                for (int ks = 0; ks < 4; ++ks) {
                    half8 vv = *(const half8*)&vth[d * 144 + ((ks * 4 + quad + d) & 15) * 8];
                    yacc[g][dt] = __builtin_amdgcn_mfma_f32_16x16x32_f16(pH[ks], vv, yacc[g][dt], 0, 0, 0);
                }
            }
        }
    }

#pragma unroll
    for (int g = 0; g < 2; ++g) {
#pragma unroll
        for (int r = 0; r < 4; ++r) {
            float s1 = yacc[g][0][r] + yacc[g][1][r] + yacc[g][2][r] + yacc[g][3][r];
            float s2 = yacc[g][0][r] * yacc[g][0][r] + yacc[g][1][r] * yacc[g][1][r] +
                       yacc[g][2][r] * yacc[g][2][r] + yacc[g][3][r] * yacc[g][3][r];
#pragma unroll
            for (int o = 1; o <= 8; o <<= 1) {
                s1 += __shfl_xor(s1, o, 64);
                s2 += __shfl_xor(s2, o, 64);
            }
            float mu = s1 * (1.f / 64.f);
            float var = fmaxf(s2 * (1.f / 64.f) - mu * mu, 0.f);
            float rs = 1.f / sqrtf(var + 1e-5f);
            int nglob = n0 + wid * 32 + g * 16 + quad * 4 + r;
            size_t grow = (size_t)(b * 1024 + nglob);
#pragma unroll
            for (int dt = 0; dt < 4; ++dt) {
                int d = dt * 16 + l15;
                float yv = (yacc[g][dt][r] - mu) * rs;
                float gt = h2f(QKVGh[grow * 2048 + 1536 + h * 64 + d]);
                float sw = gt / (1.f + expf(-gt));
                Zh[grow * 512 + h * 64 + d] = f2h(yv * sw);
            }
        }
    }
}

// ---------- final reduce: logits[b] = sum fcpart[b*1024..]; sigmoid ----------
__global__ __launch_bounds__(256) void fc_final(const float* __restrict__ fcpart,
                                                const float* __restrict__ fcb,
                                                float* __restrict__ out)
{
    __shared__ float red[4];
    int b = blockIdx.x, t = threadIdx.x;
    float4 v = *(const float4*)&fcpart[(size_t)b * 1024 + t * 4];
    float s = v.x + v.y + v.z + v.w;
    int wid = t >> 6, lane = t & 63;
#pragma unroll
    for (int o = 32; o >= 1; o >>= 1) s += __shfl_xor(s, o, 64);
    if (lane == 0) red[wid] = s;
    __syncthreads();
    if (t == 0) {
        float l = red[0] + red[1] + red[2] + red[3] + fcb[0];
        out[b] = 1.f / (1.f + expf(-l));
    }
}

extern "C" void kernel_launch(void* const* d_in, const int* in_sizes, int n_in,
                              void* d_out, int out_size, void* d_ws, size_t ws_size,
                              hipStream_t stream)
{
    const int* ids = (const int*)d_in[0];
    const float* emb = (const float*)d_in[1];
    const float* pos = (const float*)d_in[2];
    const float* ln_g = (const float*)d_in[3];
    const float* ln_b = (const float*)d_in[4];
    const float* Wq = (const float*)d_in[5];
    const float* Wk = (const float*)d_in[6];
    const float* Wv = (const float*)d_in[7];
    const float* Wg = (const float*)d_in[8];
    const float* Wo = (const float*)d_in[9];
    const float* W1 = (const float*)d_in[10];
    const float* b1 = (const float*)d_in[11];
    const float* W2 = (const float*)d_in[12];
    const float* b2 = (const float*)d_in[13];
    const float* fcW = (const float*)d_in[14];
    const float* fcb = (const float*)d_in[15];
    float* out = (float*)d_out;

    char* ws = (char*)d_ws;
    u16* WT     = (u16*)(ws);                  //  3,670,016
    u16* x0h    = (u16*)(ws + 3670016);        //  8,388,608  LN(emb) f16 (A + residual)
    u16* Zh     = (u16*)(ws + 12058624);       //  8,388,608  retention out f16
    u16* QKVGh  = (u16*)(ws + 20447232);       // 33,554,432  [8192][2048] f16
    float* fcpart = (float*)(ws + 54001664);   // 32,768
    u16* X1h = QKVGh;                           // Wo out (residual for W2)
    u16* Th  = (u16*)((char*)QKVGh + 8388608);  // ln2 out
    u16* Hh  = (u16*)((char*)QKVGh + 16777216); // W1 out
    u16* X2h = Zh;                              // Zh dead after Wo-GEMM

    // only vocab iteration i=2 is live (x overwritten each pass)
    transpose_w<<<dim3(8, 8, 7), 256, 0, stream>>>(Wq, Wk, Wv, Wg, Wo, W1, W2, WT);
    ln_kernel<<<2048, 256, 0, stream>>>(nullptr, ids, emb, pos, ln_g, ln_b, x0h, 1, nullptr, nullptr);
    gemm_f16<<<dim3(16, 64), 256, 0, stream>>>(x0h, WT, QKVGh, nullptr, nullptr, 0, 2048);
    retention_f16<<<512, 256, 0, stream>>>(QKVGh, Zh);
    gemm_f16<<<dim3(4, 64), 256, 0, stream>>>(Zh, WT + 4 * 262144, X1h, x0h, nullptr, 1, 512);
    ln_kernel<<<2048, 256, 0, stream>>>(X1h, nullptr, nullptr, nullptr, ln_g, ln_b, Th, 0, nullptr, nullptr);
    gemm_f16<<<dim3(4, 64), 256, 0, stream>>>(Th, WT + 5 * 262144, Hh, nullptr, b1, 2, 512);
    gemm_f16<<<dim3(4, 64), 256, 0, stream>>>(Hh, WT + 6 * 262144, X2h, X1h, b2, 3, 512);
    // final LN fused with FC partial dot (plain per-block store)
    ln_kernel<<<2048, 256, 0, stream>>>(X2h, nullptr, nullptr, nullptr, ln_g, ln_b, nullptr, 0, fcW, fcpart);
    fc_final<<<8, 256, 0, stream>>>(fcpart, fcb, out);
}

// Round 14
// 275.273 us; speedup vs baseline: 1.5892x; 1.0110x over previous
//
#include <hip/hip_runtime.h>
#include <math.h>

typedef unsigned short u16;
typedef __attribute__((ext_vector_type(8))) _Float16 half8;
typedef __attribute__((ext_vector_type(4))) float f32x4;
typedef __attribute__((ext_vector_type(4))) unsigned short us4;

// Inputs f32, output f32 (proven r4-13). All inter-kernel activations f16.
// r14: chunked state-form retention (kills the quadratic K/V re-read).

static __device__ __forceinline__ u16 f2h(float f) {
    _Float16 h = (_Float16)f;
    return __builtin_bit_cast(u16, h);
}
static __device__ __forceinline__ float h2f(u16 u) {
    return (float)__builtin_bit_cast(_Float16, u);
}
// async global->LDS DMA, 16B/lane; lds base wave-uniform (HW adds lane*16)
static __device__ __forceinline__ void gl_lds16(const void* g, void* l) {
    __builtin_amdgcn_global_load_lds(
        (const __attribute__((address_space(1))) void*)g,
        (__attribute__((address_space(3))) void*)l, 16, 0, 0);
}

// ---------- weight transpose: WT[w][n][k] = f16(W[w][k][n]) ----------
__global__ __launch_bounds__(256) void transpose_w(
    const float* __restrict__ Wq, const float* __restrict__ Wk, const float* __restrict__ Wv,
    const float* __restrict__ Wg, const float* __restrict__ Wo, const float* __restrict__ W1,
    const float* __restrict__ W2, u16* __restrict__ WT)
{
    __shared__ float tile[64][65];
    const float* Ws[7] = {Wq, Wk, Wv, Wg, Wo, W1, W2};
    int w = blockIdx.z;
    int k0 = blockIdx.x * 64, n0 = blockIdx.y * 64;
    const float* W = Ws[w];
    int t = threadIdx.x;
    for (int c = t; c < 4096; c += 256) {
        int row = c >> 6, col = c & 63;
        tile[row][col] = W[(size_t)(k0 + row) * 512 + n0 + col];
    }
    __syncthreads();
    for (int c = t; c < 4096; c += 256) {
        int row = c >> 6, col = c & 63;
        WT[(size_t)w * 262144 + (size_t)(n0 + row) * 512 + k0 + col] = f2h(tile[col][row]);
    }
}

// ---------- LayerNorm, row-per-wave (no LDS, no barriers); optional fused FC partial ----------
__global__ __launch_bounds__(256) void ln_kernel(
    const u16* __restrict__ xin,
    const int* __restrict__ ids, const float* __restrict__ emb, const float* __restrict__ pos,
    const float* __restrict__ gam, const float* __restrict__ bet,
    u16* __restrict__ outh, int mode,
    const float* __restrict__ fcW, float* __restrict__ fcpart)
{
    int wid = threadIdx.x >> 6, lane = threadIdx.x & 63;
    int row = blockIdx.x * 4 + wid;
    int col = lane * 8;
    float v[8];
    if (mode == 1) {
        int id = ids[2 * 8192 + row];
        const float* e = emb + (size_t)(2 * 1024 + id) * 512 + col;
        const float* p = pos + (size_t)(2 * 1024 + (row & 1023)) * 512 + col;
        float4 e0 = *(const float4*)e, e1 = *(const float4*)(e + 4);
        float4 p0 = *(const float4*)p, p1 = *(const float4*)(p + 4);
        v[0] = e0.x + p0.x; v[1] = e0.y + p0.y; v[2] = e0.z + p0.z; v[3] = e0.w + p0.w;
        v[4] = e1.x + p1.x; v[5] = e1.y + p1.y; v[6] = e1.z + p1.z; v[7] = e1.w + p1.w;
    } else {
        half8 x = *(const half8*)&xin[(size_t)row * 512 + col];
#pragma unroll
        for (int j = 0; j < 8; ++j) v[j] = (float)x[j];
    }
    float s1 = 0.f, s2 = 0.f;
#pragma unroll
    for (int j = 0; j < 8; ++j) { s1 += v[j]; s2 += v[j] * v[j]; }
#pragma unroll
    for (int o = 32; o >= 1; o >>= 1) {
        s1 += __shfl_xor(s1, o, 64);
        s2 += __shfl_xor(s2, o, 64);
    }
    float mu = s1 * (1.f / 512.f);
    float var = fmaxf(s2 * (1.f / 512.f) - mu * mu, 0.f);
    float rs = 1.f / sqrtf(var + 1e-5f);
    float4 g0 = *(const float4*)&gam[col], g1 = *(const float4*)&gam[col + 4];
    float4 b0 = *(const float4*)&bet[col], b1 = *(const float4*)&bet[col + 4];
    float gv[8] = {g0.x, g0.y, g0.z, g0.w, g1.x, g1.y, g1.z, g1.w};
    float bv[8] = {b0.x, b0.y, b0.z, b0.w, b1.x, b1.y, b1.z, b1.w};
    float y[8];
#pragma unroll
    for (int j = 0; j < 8; ++j) y[j] = (v[j] - mu) * rs * gv[j] + bv[j];
    if (outh) {
        half8 hv;
#pragma unroll
        for (int j = 0; j < 8; ++j) hv[j] = (_Float16)y[j];
        *(half8*)&outh[(size_t)row * 512 + col] = hv;
    }
    if (fcW) {
        int srow = row & 1023;
        const float* wp = &fcW[(size_t)srow * 512 + col];
        float4 w0 = *(const float4*)wp, w1 = *(const float4*)(wp + 4);
        float d = y[0] * w0.x + y[1] * w0.y + y[2] * w0.z + y[3] * w0.w +
                  y[4] * w1.x + y[5] * w1.y + y[6] * w1.z + y[7] * w1.w;
#pragma unroll
        for (int o = 32; o >= 1; o >>= 1) d += __shfl_xor(d, o, 64);
        if (lane == 0) fcpart[row] = d;
    }
}

// ---------- GEMM: outh = f16(A_f16 x B_f16^T [+ eps]); gl_lds staging, BK=64 ----------
__global__ __launch_bounds__(256) void gemm_f16(
    const u16* __restrict__ A2, const u16* __restrict__ Bg,
    u16* __restrict__ outh,
    const u16* __restrict__ res, const float* __restrict__ bias, int mode, int ostride)
{
    __shared__ u16 As[128 * 64];
    __shared__ u16 Bs[128 * 64];
    int t = threadIdx.x;
    int wid = t >> 6, lane = t & 63, quad = lane >> 4, l15 = lane & 15;
    int wm = wid >> 1, wn = wid & 1;
    int m0 = blockIdx.y * 128, n0 = blockIdx.x * 128;

    int srow = wid * 8 + (lane >> 3);
    int scol = (lane & 7) * 8;

    f32x4 acc[4][4];
#pragma unroll
    for (int a = 0; a < 4; ++a)
#pragma unroll
        for (int b = 0; b < 4; ++b) acc[a][b] = (f32x4){0.f, 0.f, 0.f, 0.f};

    for (int ki = 0; ki < 8; ++ki) {
        int k0 = ki * 64;
        __syncthreads();
#pragma unroll
        for (int i = 0; i < 4; ++i) {
            int r = i * 32 + srow;
            gl_lds16(&A2[(size_t)(m0 + r) * 512 + k0 + scol], &As[(i * 32 + wid * 8) * 64]);
            gl_lds16(&Bg[(size_t)(n0 + r) * 512 + k0 + scol], &Bs[(i * 32 + wid * 8) * 64]);
        }
        __syncthreads();
#pragma unroll
        for (int ks = 0; ks < 2; ++ks) {
            half8 af[4], bf[4];
#pragma unroll
            for (int tm = 0; tm < 4; ++tm)
                af[tm] = *(const half8*)&As[(wm * 64 + tm * 16 + l15) * 64 + ks * 32 + quad * 8];
#pragma unroll
            for (int tn = 0; tn < 4; ++tn)
                bf[tn] = *(const half8*)&Bs[(wn * 64 + tn * 16 + l15) * 64 + ks * 32 + quad * 8];
#pragma unroll
            for (int tm = 0; tm < 4; ++tm)
#pragma unroll
                for (int tn = 0; tn < 4; ++tn)
                    acc[tm][tn] = __builtin_amdgcn_mfma_f32_16x16x32_f16(af[tm], bf[tn], acc[tm][tn], 0, 0, 0);
        }
    }

#pragma unroll
    for (int tm = 0; tm < 4; ++tm) {
#pragma unroll
        for (int tn = 0; tn < 4; ++tn) {
            int n = n0 + wn * 64 + tn * 16 + l15;
            int mbase = m0 + wm * 64 + tm * 16 + quad * 4;
#pragma unroll
            for (int r = 0; r < 4; ++r) {
                int m = mbase + r;
                float v = acc[tm][tn][r];
                if (mode == 1) v += h2f(res[(size_t)m * 512 + n]);
                else if (mode == 2) v = fmaxf(v + bias[n], 0.f);
                else if (mode == 3) v += bias[n] + h2f(res[(size_t)m * 512 + n]);
                outh[(size_t)m * ostride + n] = f2h(v);
            }
        }
    }
}

// ---------- state kernel: per (b,h), chunked decayed-state prefix ----------
// T'_c[d'][d] = sum_{m in chunk c} v[m][d'] * k[m][d]*gamma^(127-mlocal)
// S_{c+1} = gamma^128 * S_c + T_c (held in VGPRs); Sst[bh][c+1][d'][d] = f16(S)
__global__ __launch_bounds__(256) void state_kernel(
    const u16* __restrict__ QKVGh, u16* __restrict__ Sst)
{
    __shared__ u16 kth[64 * 144];   // K^T (decay-scaled) [d][m], rotation-swizzled
    __shared__ u16 vth[64 * 144];   // V^T [d][m], rotation-swizzled
    int t = threadIdx.x;
    int wid = t >> 6, lane = t & 63, quad = lane >> 4, l15 = lane & 15;
    int bh = blockIdx.x, b = bh >> 3, h = bh & 7;
    float gamma = 1.f - exp2f(-(float)(5 + h));
    float l2g = log2f(gamma);
    float g128 = exp2f(128.f * l2g);

    f32x4 S[4];
#pragma unroll
    for (int dt = 0; dt < 4; ++dt) S[dt] = (f32x4){0.f, 0.f, 0.f, 0.f};

    for (int c = 0; c < 8; ++c) {
        __syncthreads();
        for (int cc = t; cc < 2048; cc += 256) {
            int d = cc & 63, mseg = cc >> 6;
            size_t gbase = (size_t)(b * 1024 + c * 128 + mseg * 4) * 2048 + h * 64 + d;
            us4 k4, v4;
#pragma unroll
            for (int i = 0; i < 4; ++i) {
                float kv = h2f(QKVGh[gbase + 512 + (size_t)i * 2048]);
                k4[i] = f2h(kv * exp2f((float)(127 - (mseg * 4 + i)) * l2g));
                v4[i] = QKVGh[gbase + 1024 + (size_t)i * 2048];
            }
            int base = d * 144 + (((mseg >> 1) + d) & 15) * 8 + (mseg & 1) * 4;
            *(us4*)&kth[base] = k4;
            *(us4*)&vth[base] = v4;
        }
        __syncthreads();
        f32x4 T[4];
#pragma unroll
        for (int dt = 0; dt < 4; ++dt) T[dt] = (f32x4){0.f, 0.f, 0.f, 0.f};
        int ra = wid * 16 + l15;   // A rows: d' = wid*16 + l15
#pragma unroll
        for (int ks = 0; ks < 4; ++ks) {
            half8 av = *(const half8*)&vth[ra * 144 + ((ks * 4 + quad + ra) & 15) * 8];
#pragma unroll
            for (int dt = 0; dt < 4; ++dt) {
                int rb = dt * 16 + l15;
                half8 bk = *(const half8*)&kth[rb * 144 + ((ks * 4 + quad + rb) & 15) * 8];
                T[dt] = __builtin_amdgcn_mfma_f32_16x16x32_f16(av, bk, T[dt], 0, 0, 0);
            }
        }
#pragma unroll
        for (int dt = 0; dt < 4; ++dt)
#pragma unroll
            for (int r = 0; r < 4; ++r)
                S[dt][r] = g128 * S[dt][r] + T[dt][r];
        if (c < 7) {
#pragma unroll
            for (int dt = 0; dt < 4; ++dt)
#pragma unroll
                for (int r = 0; r < 4; ++r) {
                    int i = wid * 16 + quad * 4 + r;   // d' (D row)
                    int j = dt * 16 + l15;             // d  (D col)
                    Sst[(((size_t)bh * 8 + c + 1) * 64 + i) * 64 + j] = f2h(S[dt][r]);
                }
        }
    }
}

// ---------- retention: single chunk intra + state inter; q-tile = chunk = 128 ----------
__global__ __launch_bounds__(256) void retention_f16(
    const u16* __restrict__ QKVGh, const u16* __restrict__ Sst, u16* __restrict__ Zh)
{
    __shared__ u16 kh[128 * 72];       // K tile [m][d], stride 72
    __shared__ u16 vth[64 * 144];      // V^T [d][m=128], rotation-swizzled
    __shared__ u16 sst[64 * 72];       // state tile [d'][d], stride 72
    __shared__ u16 ph[4][16 * 132];    // per-wave per-group P

    int t = threadIdx.x;
    int wid = t >> 6, lane = t & 63, quad = lane >> 4, l15 = lane & 15;
    int bh = blockIdx.x >> 3, qt = blockIdx.x & 7;
    int b = bh >> 3, h = bh & 7;
    int n0 = qt * 128;

    float gamma = 1.f - exp2f(-(float)(5 + h));
    float l2g = log2f(gamma);

    // Q frags + inter-scaled copy: qs_row = gamma^(local+1)/8
    half8 aH[2][2], aHs[2][2];
#pragma unroll
    for (int g = 0; g < 2; ++g) {
        int rowloc = wid * 32 + g * 16 + l15;
        int qrow = b * 1024 + n0 + rowloc;
        const u16* qp = QKVGh + (size_t)qrow * 2048 + h * 64;
        float qs = exp2f((float)(rowloc + 1) * l2g - 3.f);
#pragma unroll
        for (int ks = 0; ks < 2; ++ks) {
            aH[g][ks] = *(const half8*)&qp[ks * 32 + quad * 8];
#pragma unroll
            for (int j = 0; j < 8; ++j)
                aHs[g][ks][j] = (_Float16)((float)aH[g][ks][j] * qs);
        }
    }

    // stage K tile, V^T tile (own chunk), state tile
    for (int c = t; c < 2048; c += 256) {
        int row = c >> 4, c4 = c & 15;
        size_t grow = (size_t)(b * 1024 + n0 + row) * 2048;
        *(us4*)&kh[row * 72 + c4 * 4] = *(const us4*)&QKVGh[grow + 512 + h * 64 + c4 * 4];
    }
    for (int c = t; c < 2048; c += 256) {
        int d = c & 63, mseg = c >> 6;
        size_t gbase = (size_t)(b * 1024 + n0 + mseg * 4) * 2048 + 1024 + h * 64 + d;
        us4 v4 = {QKVGh[gbase], QKVGh[gbase + 2048],
                  QKVGh[gbase + 4096], QKVGh[gbase + 6144]};
        int base = d * 144 + (((mseg >> 1) + d) & 15) * 8 + (mseg & 1) * 4;
        *(us4*)&vth[base] = v4;
    }
    if (qt > 0) {
        for (int c = t; c < 1024; c += 256) {
            int row = c >> 4, c4 = c & 15;
            *(us4*)&sst[row * 72 + c4 * 4] =
                *(const us4*)&Sst[(((size_t)bh * 8 + qt) * 64 + row) * 64 + c4 * 4];
        }
    }
    __syncthreads();

    f32x4 yacc[2][4];
#pragma unroll
    for (int g = 0; g < 2; ++g)
#pragma unroll
        for (int dt = 0; dt < 4; ++dt) yacc[g][dt] = (f32x4){0.f, 0.f, 0.f, 0.f};

    // inter-chunk: y += qs . S   (B rows d' from sst, k = d)
    if (qt > 0) {
#pragma unroll
        for (int ks = 0; ks < 2; ++ks) {
            half8 sf[4];
#pragma unroll
            for (int dt = 0; dt < 4; ++dt)
                sf[dt] = *(const half8*)&sst[(dt * 16 + l15) * 72 + ks * 32 + quad * 8];
#pragma unroll
            for (int g = 0; g < 2; ++g)
#pragma unroll
                for (int dt = 0; dt < 4; ++dt)
                    yacc[g][dt] = __builtin_amdgcn_mfma_f32_16x16x32_f16(aHs[g][ks], sf[dt], yacc[g][dt], 0, 0, 0);
        }
    }

    // intra-chunk: QK^T -> decay -> P -> PV
#pragma unroll
    for (int g = 0; g < 2; ++g) {
        f32x4 sacc[8];
#pragma unroll
        for (int tn = 0; tn < 8; ++tn) sacc[tn] = (f32x4){0.f, 0.f, 0.f, 0.f};
#pragma unroll
        for (int tn = 0; tn < 8; ++tn)
#pragma unroll
            for (int ks = 0; ks < 2; ++ks) {
                half8 bH = *(const half8*)&kh[(tn * 16 + l15) * 72 + ks * 32 + quad * 8];
                sacc[tn] = __builtin_amdgcn_mfma_f32_16x16x32_f16(aH[g][ks], bH, sacc[tn], 0, 0, 0);
            }
#pragma unroll
        for (int tn = 0; tn < 8; ++tn) {
            int mloc = tn * 16 + l15;
#pragma unroll
            for (int r = 0; r < 4; ++r) {
                int nloc = wid * 32 + g * 16 + quad * 4 + r;
                int diff = nloc - mloc;
                float p = (diff >= 0) ? sacc[tn][r] * exp2f((float)diff * l2g - 3.0f) : 0.f;
                ph[wid][(quad * 4 + r) * 132 + tn * 16 + l15] = f2h(p);
            }
        }
        half8 pH[4];
#pragma unroll
        for (int ks = 0; ks < 4; ++ks)
            pH[ks] = *(const half8*)&ph[wid][l15 * 132 + ks * 32 + quad * 8];
#pragma unroll
        for (int dt = 0; dt < 4; ++dt) {
            int d = dt * 16 + l15;
#pragma unroll
            for (int ks = 0; ks < 4; ++ks) {
                half8 vv = *(const half8*)&vth[d * 144 + ((ks * 4 + quad + d) & 15) * 8];
                yacc[g][dt] = __builtin_amdgcn_mfma_f32_16x16x32_f16(pH[ks], vv, yacc[g][dt], 0, 0, 0);
            }
        }
    }

    // per-q-row groupnorm + swish gate + f16 store
#pragma unroll
    for (int g = 0; g < 2; ++g) {
#pragma unroll
        for (int r = 0; r < 4; ++r) {
            float s1 = yacc[g][0][r] + yacc[g][1][r] + yacc[g][2][r] + yacc[g][3][r];
            float s2 = yacc[g][0][r] * yacc[g][0][r] + yacc[g][1][r] * yacc[g][1][r] +
                       yacc[g][2][r] * yacc[g][2][r] + yacc[g][3][r] * yacc[g][3][r];
#pragma unroll
            for (int o = 1; o <= 8; o <<= 1) {
                s1 += __shfl_xor(s1, o, 64);
                s2 += __shfl_xor(s2, o, 64);
            }
            float mu = s1 * (1.f / 64.f);
            float var = fmaxf(s2 * (1.f / 64.f) - mu * mu, 0.f);
            float rs = 1.f / sqrtf(var + 1e-5f);
            int nglob = n0 + wid * 32 + g * 16 + quad * 4 + r;
            size_t grow = (size_t)(b * 1024 + nglob);
#pragma unroll
            for (int dt = 0; dt < 4; ++dt) {
                int d = dt * 16 + l15;
                float yv = (yacc[g][dt][r] - mu) * rs;
                float gt = h2f(QKVGh[grow * 2048 + 1536 + h * 64 + d]);
                float sw = gt / (1.f + expf(-gt));
                Zh[grow * 512 + h * 64 + d] = f2h(yv * sw);
            }
        }
    }
}

// ---------- final reduce ----------
__global__ __launch_bounds__(256) void fc_final(const float* __restrict__ fcpart,
                                                const float* __restrict__ fcb,
                                                float* __restrict__ out)
{
    __shared__ float red[4];
    int b = blockIdx.x, t = threadIdx.x;
    float4 v = *(const float4*)&fcpart[(size_t)b * 1024 + t * 4];
    float s = v.x + v.y + v.z + v.w;
    int wid = t >> 6, lane = t & 63;
#pragma unroll
    for (int o = 32; o >= 1; o >>= 1) s += __shfl_xor(s, o, 64);
    if (lane == 0) red[wid] = s;
    __syncthreads();
    if (t == 0) {
        float l = red[0] + red[1] + red[2] + red[3] + fcb[0];
        out[b] = 1.f / (1.f + expf(-l));
    }
}

extern "C" void kernel_launch(void* const* d_in, const int* in_sizes, int n_in,
                              void* d_out, int out_size, void* d_ws, size_t ws_size,
                              hipStream_t stream)
{
    const int* ids = (const int*)d_in[0];
    const float* emb = (const float*)d_in[1];
    const float* pos = (const float*)d_in[2];
    const float* ln_g = (const float*)d_in[3];
    const float* ln_b = (const float*)d_in[4];
    const float* Wq = (const float*)d_in[5];
    const float* Wk = (const float*)d_in[6];
    const float* Wv = (const float*)d_in[7];
    const float* Wg = (const float*)d_in[8];
    const float* Wo = (const float*)d_in[9];
    const float* W1 = (const float*)d_in[10];
    const float* b1 = (const float*)d_in[11];
    const float* W2 = (const float*)d_in[12];
    const float* b2 = (const float*)d_in[13];
    const float* fcW = (const float*)d_in[14];
    const float* fcb = (const float*)d_in[15];
    float* out = (float*)d_out;

    char* ws = (char*)d_ws;
    u16* WT     = (u16*)(ws);                  //  3,670,016
    u16* x0h    = (u16*)(ws + 3670016);        //  8,388,608  LN(emb) f16 (A + residual)
    u16* Zh     = (u16*)(ws + 12058624);       //  8,388,608  retention out f16
    u16* QKVGh  = (u16*)(ws + 20447232);       // 33,554,432  [8192][2048] f16
    float* fcpart = (float*)(ws + 54001664);   // 32,768
    u16* Sst    = (u16*)(ws + 54034432);       //  4,194,304  [64 bh][8][64][64] f16
    u16* X1h = QKVGh;                           // Wo out (residual for W2)
    u16* Th  = (u16*)((char*)QKVGh + 8388608);  // ln2 out
    u16* Hh  = (u16*)((char*)QKVGh + 16777216); // W1 out
    u16* X2h = Zh;                              // Zh dead after Wo-GEMM

    // only vocab iteration i=2 is live (x overwritten each pass)
    transpose_w<<<dim3(8, 8, 7), 256, 0, stream>>>(Wq, Wk, Wv, Wg, Wo, W1, W2, WT);
    ln_kernel<<<2048, 256, 0, stream>>>(nullptr, ids, emb, pos, ln_g, ln_b, x0h, 1, nullptr, nullptr);
    gemm_f16<<<dim3(16, 64), 256, 0, stream>>>(x0h, WT, QKVGh, nullptr, nullptr, 0, 2048);
    state_kernel<<<64, 256, 0, stream>>>(QKVGh, Sst);
    retention_f16<<<512, 256, 0, stream>>>(QKVGh, Sst, Zh);
    gemm_f16<<<dim3(4, 64), 256, 0, stream>>>(Zh, WT + 4 * 262144, X1h, x0h, nullptr, 1, 512);
    ln_kernel<<<2048, 256, 0, stream>>>(X1h, nullptr, nullptr, nullptr, ln_g, ln_b, Th, 0, nullptr, nullptr);
    gemm_f16<<<dim3(4, 64), 256, 0, stream>>>(Th, WT + 5 * 262144, Hh, nullptr, b1, 2, 512);
    gemm_f16<<<dim3(4, 64), 256, 0, stream>>>(Hh, WT + 6 * 262144, X2h, X1h, b2, 3, 512);
    ln_kernel<<<2048, 256, 0, stream>>>(X2h, nullptr, nullptr, nullptr, ln_g, ln_b, nullptr, 0, fcW, fcpart);
    fc_final<<<8, 256, 0, stream>>>(fcpart, fcb, out);
}

// Round 15
// 250.966 us; speedup vs baseline: 1.7431x; 1.0969x over previous
//
#include <hip/hip_runtime.h>
#include <math.h>

typedef unsigned short u16;
typedef __attribute__((ext_vector_type(8))) _Float16 half8;
typedef __attribute__((ext_vector_type(4))) float f32x4;
typedef __attribute__((ext_vector_type(4))) unsigned short us4;

// Inputs f32, output f32 (proven r4-14). All inter-kernel activations f16.
// r15: parallel state path (chunk_t 512 blocks + tiny prefix) + retention LDS diet.

static __device__ __forceinline__ u16 f2h(float f) {
    _Float16 h = (_Float16)f;
    return __builtin_bit_cast(u16, h);
}
static __device__ __forceinline__ float h2f(u16 u) {
    return (float)__builtin_bit_cast(_Float16, u);
}
static __device__ __forceinline__ void gl_lds16(const void* g, void* l) {
    __builtin_amdgcn_global_load_lds(
        (const __attribute__((address_space(1))) void*)g,
        (__attribute__((address_space(3))) void*)l, 16, 0, 0);
}

// ---------- weight transpose: WT[w][n][k] = f16(W[w][k][n]) ----------
__global__ __launch_bounds__(256) void transpose_w(
    const float* __restrict__ Wq, const float* __restrict__ Wk, const float* __restrict__ Wv,
    const float* __restrict__ Wg, const float* __restrict__ Wo, const float* __restrict__ W1,
    const float* __restrict__ W2, u16* __restrict__ WT)
{
    __shared__ float tile[64][65];
    const float* Ws[7] = {Wq, Wk, Wv, Wg, Wo, W1, W2};
    int w = blockIdx.z;
    int k0 = blockIdx.x * 64, n0 = blockIdx.y * 64;
    const float* W = Ws[w];
    int t = threadIdx.x;
    for (int c = t; c < 4096; c += 256) {
        int row = c >> 6, col = c & 63;
        tile[row][col] = W[(size_t)(k0 + row) * 512 + n0 + col];
    }
    __syncthreads();
    for (int c = t; c < 4096; c += 256) {
        int row = c >> 6, col = c & 63;
        WT[(size_t)w * 262144 + (size_t)(n0 + row) * 512 + k0 + col] = f2h(tile[col][row]);
    }
}

// ---------- LayerNorm, row-per-wave; optional fused FC partial ----------
__global__ __launch_bounds__(256) void ln_kernel(
    const u16* __restrict__ xin,
    const int* __restrict__ ids, const float* __restrict__ emb, const float* __restrict__ pos,
    const float* __restrict__ gam, const float* __restrict__ bet,
    u16* __restrict__ outh, int mode,
    const float* __restrict__ fcW, float* __restrict__ fcpart)
{
    int wid = threadIdx.x >> 6, lane = threadIdx.x & 63;
    int row = blockIdx.x * 4 + wid;
    int col = lane * 8;
    float v[8];
    if (mode == 1) {
        int id = ids[2 * 8192 + row];
        const float* e = emb + (size_t)(2 * 1024 + id) * 512 + col;
        const float* p = pos + (size_t)(2 * 1024 + (row & 1023)) * 512 + col;
        float4 e0 = *(const float4*)e, e1 = *(const float4*)(e + 4);
        float4 p0 = *(const float4*)p, p1 = *(const float4*)(p + 4);
        v[0] = e0.x + p0.x; v[1] = e0.y + p0.y; v[2] = e0.z + p0.z; v[3] = e0.w + p0.w;
        v[4] = e1.x + p1.x; v[5] = e1.y + p1.y; v[6] = e1.z + p1.z; v[7] = e1.w + p1.w;
    } else {
        half8 x = *(const half8*)&xin[(size_t)row * 512 + col];
#pragma unroll
        for (int j = 0; j < 8; ++j) v[j] = (float)x[j];
    }
    float s1 = 0.f, s2 = 0.f;
#pragma unroll
    for (int j = 0; j < 8; ++j) { s1 += v[j]; s2 += v[j] * v[j]; }
#pragma unroll
    for (int o = 32; o >= 1; o >>= 1) {
        s1 += __shfl_xor(s1, o, 64);
        s2 += __shfl_xor(s2, o, 64);
    }
    float mu = s1 * (1.f / 512.f);
    float var = fmaxf(s2 * (1.f / 512.f) - mu * mu, 0.f);
    float rs = 1.f / sqrtf(var + 1e-5f);
    float4 g0 = *(const float4*)&gam[col], g1 = *(const float4*)&gam[col + 4];
    float4 b0 = *(const float4*)&bet[col], b1 = *(const float4*)&bet[col + 4];
    float gv[8] = {g0.x, g0.y, g0.z, g0.w, g1.x, g1.y, g1.z, g1.w};
    float bv[8] = {b0.x, b0.y, b0.z, b0.w, b1.x, b1.y, b1.z, b1.w};
    float y[8];
#pragma unroll
    for (int j = 0; j < 8; ++j) y[j] = (v[j] - mu) * rs * gv[j] + bv[j];
    if (outh) {
        half8 hv;
#pragma unroll
        for (int j = 0; j < 8; ++j) hv[j] = (_Float16)y[j];
        *(half8*)&outh[(size_t)row * 512 + col] = hv;
    }
    if (fcW) {
        int srow = row & 1023;
        const float* wp = &fcW[(size_t)srow * 512 + col];
        float4 w0 = *(const float4*)wp, w1 = *(const float4*)(wp + 4);
        float d = y[0] * w0.x + y[1] * w0.y + y[2] * w0.z + y[3] * w0.w +
                  y[4] * w1.x + y[5] * w1.y + y[6] * w1.z + y[7] * w1.w;
#pragma unroll
        for (int o = 32; o >= 1; o >>= 1) d += __shfl_xor(d, o, 64);
        if (lane == 0) fcpart[row] = d;
    }
}

// ---------- GEMM: outh = f16(A_f16 x B_f16^T [+ eps]); gl_lds staging, BK=64 ----------
__global__ __launch_bounds__(256) void gemm_f16(
    const u16* __restrict__ A2, const u16* __restrict__ Bg,
    u16* __restrict__ outh,
    const u16* __restrict__ res, const float* __restrict__ bias, int mode, int ostride)
{
    __shared__ u16 As[128 * 64];
    __shared__ u16 Bs[128 * 64];
    int t = threadIdx.x;
    int wid = t >> 6, lane = t & 63, quad = lane >> 4, l15 = lane & 15;
    int wm = wid >> 1, wn = wid & 1;
    int m0 = blockIdx.y * 128, n0 = blockIdx.x * 128;

    int srow = wid * 8 + (lane >> 3);
    int scol = (lane & 7) * 8;

    f32x4 acc[4][4];
#pragma unroll
    for (int a = 0; a < 4; ++a)
#pragma unroll
        for (int b = 0; b < 4; ++b) acc[a][b] = (f32x4){0.f, 0.f, 0.f, 0.f};

    for (int ki = 0; ki < 8; ++ki) {
        int k0 = ki * 64;
        __syncthreads();
#pragma unroll
        for (int i = 0; i < 4; ++i) {
            int r = i * 32 + srow;
            gl_lds16(&A2[(size_t)(m0 + r) * 512 + k0 + scol], &As[(i * 32 + wid * 8) * 64]);
            gl_lds16(&Bg[(size_t)(n0 + r) * 512 + k0 + scol], &Bs[(i * 32 + wid * 8) * 64]);
        }
        __syncthreads();
#pragma unroll
        for (int ks = 0; ks < 2; ++ks) {
            half8 af[4], bf[4];
#pragma unroll
            for (int tm = 0; tm < 4; ++tm)
                af[tm] = *(const half8*)&As[(wm * 64 + tm * 16 + l15) * 64 + ks * 32 + quad * 8];
#pragma unroll
            for (int tn = 0; tn < 4; ++tn)
                bf[tn] = *(const half8*)&Bs[(wn * 64 + tn * 16 + l15) * 64 + ks * 32 + quad * 8];
#pragma unroll
            for (int tm = 0; tm < 4; ++tm)
#pragma unroll
                for (int tn = 0; tn < 4; ++tn)
                    acc[tm][tn] = __builtin_amdgcn_mfma_f32_16x16x32_f16(af[tm], bf[tn], acc[tm][tn], 0, 0, 0);
        }
    }

#pragma unroll
    for (int tm = 0; tm < 4; ++tm) {
#pragma unroll
        for (int tn = 0; tn < 4; ++tn) {
            int n = n0 + wn * 64 + tn * 16 + l15;
            int mbase = m0 + wm * 64 + tm * 16 + quad * 4;
#pragma unroll
            for (int r = 0; r < 4; ++r) {
                int m = mbase + r;
                float v = acc[tm][tn][r];
                if (mode == 1) v += h2f(res[(size_t)m * 512 + n]);
                else if (mode == 2) v = fmaxf(v + bias[n], 0.f);
                else if (mode == 3) v += bias[n] + h2f(res[(size_t)m * 512 + n]);
                outh[(size_t)m * ostride + n] = f2h(v);
            }
        }
    }
}

// ---------- chunk T: per (b,h,c) parallel — T_c[d'][d] = sum_m v[m][d']*k[m][d]*g^(127-mloc) ----------
__global__ __launch_bounds__(256) void chunk_t(
    const u16* __restrict__ QKVGh, u16* __restrict__ Tst)
{
    __shared__ u16 kth[64 * 144];   // K^T (decay-scaled) [d][m], rotation-swizzled
    __shared__ u16 vth[64 * 144];   // V^T [d][m], rotation-swizzled
    int t = threadIdx.x;
    int wid = t >> 6, lane = t & 63, quad = lane >> 4, l15 = lane & 15;
    int bh = blockIdx.x >> 3, c = blockIdx.x & 7;
    int b = bh >> 3, h = bh & 7;
    float gamma = 1.f - exp2f(-(float)(5 + h));
    float l2g = log2f(gamma);

    for (int cc = t; cc < 2048; cc += 256) {
        int d = cc & 63, mseg = cc >> 6;
        size_t gbase = (size_t)(b * 1024 + c * 128 + mseg * 4) * 2048 + h * 64 + d;
        us4 k4, v4;
#pragma unroll
        for (int i = 0; i < 4; ++i) {
            float kv = h2f(QKVGh[gbase + 512 + (size_t)i * 2048]);
            k4[i] = f2h(kv * exp2f((float)(127 - (mseg * 4 + i)) * l2g));
            v4[i] = QKVGh[gbase + 1024 + (size_t)i * 2048];
        }
        int base = d * 144 + (((mseg >> 1) + d) & 15) * 8 + (mseg & 1) * 4;
        *(us4*)&kth[base] = k4;
        *(us4*)&vth[base] = v4;
    }
    __syncthreads();
    f32x4 T[4];
#pragma unroll
    for (int dt = 0; dt < 4; ++dt) T[dt] = (f32x4){0.f, 0.f, 0.f, 0.f};
    int ra = wid * 16 + l15;   // A rows: d'
#pragma unroll
    for (int ks = 0; ks < 4; ++ks) {
        half8 av = *(const half8*)&vth[ra * 144 + ((ks * 4 + quad + ra) & 15) * 8];
#pragma unroll
        for (int dt = 0; dt < 4; ++dt) {
            int rb = dt * 16 + l15;
            half8 bk = *(const half8*)&kth[rb * 144 + ((ks * 4 + quad + rb) & 15) * 8];
            T[dt] = __builtin_amdgcn_mfma_f32_16x16x32_f16(av, bk, T[dt], 0, 0, 0);
        }
    }
#pragma unroll
    for (int dt = 0; dt < 4; ++dt)
#pragma unroll
        for (int r = 0; r < 4; ++r) {
            int i = wid * 16 + quad * 4 + r;   // d' (D row)
            int j = dt * 16 + l15;             // d  (D col)
            Tst[(((size_t)bh * 8 + c) * 64 + i) * 64 + j] = f2h(T[dt][r]);
        }
}

// ---------- state prefix: S_c = g^128 * S_{c-1} + T_{c-1}; elementwise, 64 blocks ----------
__global__ __launch_bounds__(256) void state_prefix(
    const u16* __restrict__ Tst, u16* __restrict__ Sst)
{
    int bh = blockIdx.x, h = bh & 7;
    int t = threadIdx.x;
    float gamma = 1.f - exp2f(-(float)(5 + h));
    float g128 = exp2f(128.f * log2f(gamma));
    size_t base = (size_t)bh * 8 * 4096 + t * 16;
    float S[16];
#pragma unroll
    for (int j = 0; j < 16; ++j) S[j] = 0.f;
    for (int c = 1; c < 8; ++c) {
        half8 t0 = *(const half8*)&Tst[base + (size_t)(c - 1) * 4096];
        half8 t1 = *(const half8*)&Tst[base + (size_t)(c - 1) * 4096 + 8];
        half8 s0, s1;
#pragma unroll
        for (int j = 0; j < 8; ++j) {
            S[j] = g128 * S[j] + (float)t0[j];
            S[8 + j] = g128 * S[8 + j] + (float)t1[j];
            s0[j] = (_Float16)S[j];
            s1[j] = (_Float16)S[8 + j];
        }
        *(half8*)&Sst[base + (size_t)c * 4096] = s0;
        *(half8*)&Sst[base + (size_t)c * 4096 + 8] = s1;
    }
}

// ---------- retention: single chunk intra + state inter; LDS 51.7 KB -> 3 blocks/CU ----------
__global__ __launch_bounds__(256) void retention_f16(
    const u16* __restrict__ QKVGh, const u16* __restrict__ Sst, u16* __restrict__ Zh)
{
    __shared__ u16 kh[128 * 64];       // K tile [m][d], unpadded (gl_lds layout)
    __shared__ u16 vth[64 * 144];      // V^T [d][m=128], rotation-swizzled
    __shared__ u16 ph[4][16 * 132];    // per-wave per-group P

    int t = threadIdx.x;
    int wid = t >> 6, lane = t & 63, quad = lane >> 4, l15 = lane & 15;
    int bh = blockIdx.x >> 3, qt = blockIdx.x & 7;
    int b = bh >> 3, h = bh & 7;
    int n0 = qt * 128;

    float gamma = 1.f - exp2f(-(float)(5 + h));
    float l2g = log2f(gamma);

    // K tile via global_load_lds (contiguous lane*16B, m97 pattern)
    {
        int srow = wid * 8 + (lane >> 3);
        int scol = (lane & 7) * 8;
#pragma unroll
        for (int i = 0; i < 4; ++i) {
            int r = i * 32 + srow;
            gl_lds16(&QKVGh[(size_t)(b * 1024 + n0 + r) * 2048 + 512 + h * 64 + scol],
                     &kh[(i * 32 + wid * 8) * 64]);
        }
    }
    // V^T tile: manual transpose + rotation swizzle
    for (int c = t; c < 2048; c += 256) {
        int d = c & 63, mseg = c >> 6;
        size_t gbase = (size_t)(b * 1024 + n0 + mseg * 4) * 2048 + 1024 + h * 64 + d;
        us4 v4 = {QKVGh[gbase], QKVGh[gbase + 2048],
                  QKVGh[gbase + 4096], QKVGh[gbase + 6144]};
        int base = d * 144 + (((mseg >> 1) + d) & 15) * 8 + (mseg & 1) * 4;
        *(us4*)&vth[base] = v4;
    }

    // Q frags + inter-scaled copy (registers, overlap with staging)
    half8 aH[2][2], aHs[2][2];
#pragma unroll
    for (int g = 0; g < 2; ++g) {
        int rowloc = wid * 32 + g * 16 + l15;
        int qrow = b * 1024 + n0 + rowloc;
        const u16* qp = QKVGh + (size_t)qrow * 2048 + h * 64;
        float qs = exp2f((float)(rowloc + 1) * l2g - 3.f);
#pragma unroll
        for (int ks = 0; ks < 2; ++ks) {
            aH[g][ks] = *(const half8*)&qp[ks * 32 + quad * 8];
#pragma unroll
            for (int j = 0; j < 8; ++j)
                aHs[g][ks][j] = (_Float16)((float)aH[g][ks][j] * qs);
        }
    }
    // state B-frags: direct register loads (L2-resident Sst)
    half8 sf[2][4];
    if (qt > 0) {
        const u16* sp = &Sst[((size_t)bh * 8 + qt) * 4096];
#pragma unroll
        for (int ks = 0; ks < 2; ++ks)
#pragma unroll
            for (int dt = 0; dt < 4; ++dt)
                sf[ks][dt] = *(const half8*)&sp[(dt * 16 + l15) * 64 + ks * 32 + quad * 8];
    }
    __syncthreads();

    f32x4 yacc[2][4];
#pragma unroll
    for (int g = 0; g < 2; ++g)
#pragma unroll
        for (int dt = 0; dt < 4; ++dt) yacc[g][dt] = (f32x4){0.f, 0.f, 0.f, 0.f};

    // inter-chunk: y += qs . S
    if (qt > 0) {
#pragma unroll
        for (int ks = 0; ks < 2; ++ks)
#pragma unroll
            for (int g = 0; g < 2; ++g)
#pragma unroll
                for (int dt = 0; dt < 4; ++dt)
                    yacc[g][dt] = __builtin_amdgcn_mfma_f32_16x16x32_f16(aHs[g][ks], sf[ks][dt], yacc[g][dt], 0, 0, 0);
    }

    // intra-chunk: QK^T -> decay -> P -> PV
#pragma unroll
    for (int g = 0; g < 2; ++g) {
        f32x4 sacc[8];
#pragma unroll
        for (int tn = 0; tn < 8; ++tn) sacc[tn] = (f32x4){0.f, 0.f, 0.f, 0.f};
#pragma unroll
        for (int tn = 0; tn < 8; ++tn)
#pragma unroll
            for (int ks = 0; ks < 2; ++ks) {
                half8 bH = *(const half8*)&kh[(tn * 16 + l15) * 64 + ks * 32 + quad * 8];
                sacc[tn] = __builtin_amdgcn_mfma_f32_16x16x32_f16(aH[g][ks], bH, sacc[tn], 0, 0, 0);
            }
#pragma unroll
        for (int tn = 0; tn < 8; ++tn) {
            int mloc = tn * 16 + l15;
#pragma unroll
            for (int r = 0; r < 4; ++r) {
                int nloc = wid * 32 + g * 16 + quad * 4 + r;
                int diff = nloc - mloc;
                float p = (diff >= 0) ? sacc[tn][r] * exp2f((float)diff * l2g - 3.0f) : 0.f;
                ph[wid][(quad * 4 + r) * 132 + tn * 16 + l15] = f2h(p);
            }
        }
        half8 pH[4];
#pragma unroll
        for (int ks = 0; ks < 4; ++ks)
            pH[ks] = *(const half8*)&ph[wid][l15 * 132 + ks * 32 + quad * 8];
#pragma unroll
        for (int dt = 0; dt < 4; ++dt) {
            int d = dt * 16 + l15;
#pragma unroll
            for (int ks = 0; ks < 4; ++ks) {
                half8 vv = *(const half8*)&vth[d * 144 + ((ks * 4 + quad + d) & 15) * 8];
                yacc[g][dt] = __builtin_amdgcn_mfma_f32_16x16x32_f16(pH[ks], vv, yacc[g][dt], 0, 0, 0);
            }
        }
    }

    // per-q-row groupnorm + swish gate + f16 store
#pragma unroll
    for (int g = 0; g < 2; ++g) {
#pragma unroll
        for (int r = 0; r < 4; ++r) {
            float s1 = yacc[g][0][r] + yacc[g][1][r] + yacc[g][2][r] + yacc[g][3][r];
            float s2 = yacc[g][0][r] * yacc[g][0][r] + yacc[g][1][r] * yacc[g][1][r] +
                       yacc[g][2][r] * yacc[g][2][r] + yacc[g][3][r] * yacc[g][3][r];
#pragma unroll
            for (int o = 1; o <= 8; o <<= 1) {
                s1 += __shfl_xor(s1, o, 64);
                s2 += __shfl_xor(s2, o, 64);
            }
            float mu = s1 * (1.f / 64.f);
            float var = fmaxf(s2 * (1.f / 64.f) - mu * mu, 0.f);
            float rs = 1.f / sqrtf(var + 1e-5f);
            int nglob = n0 + wid * 32 + g * 16 + quad * 4 + r;
            size_t grow = (size_t)(b * 1024 + nglob);
#pragma unroll
            for (int dt = 0; dt < 4; ++dt) {
                int d = dt * 16 + l15;
                float yv = (yacc[g][dt][r] - mu) * rs;
                float gt = h2f(QKVGh[grow * 2048 + 1536 + h * 64 + d]);
                float sw = gt / (1.f + expf(-gt));
                Zh[grow * 512 + h * 64 + d] = f2h(yv * sw);
            }
        }
    }
}

// ---------- final reduce ----------
__global__ __launch_bounds__(256) void fc_final(const float* __restrict__ fcpart,
                                                const float* __restrict__ fcb,
                                                float* __restrict__ out)
{
    __shared__ float red[4];
    int b = blockIdx.x, t = threadIdx.x;
    float4 v = *(const float4*)&fcpart[(size_t)b * 1024 + t * 4];
    float s = v.x + v.y + v.z + v.w;
    int wid = t >> 6, lane = t & 63;
#pragma unroll
    for (int o = 32; o >= 1; o >>= 1) s += __shfl_xor(s, o, 64);
    if (lane == 0) red[wid] = s;
    __syncthreads();
    if (t == 0) {
        float l = red[0] + red[1] + red[2] + red[3] + fcb[0];
        out[b] = 1.f / (1.f + expf(-l));
    }
}

extern "C" void kernel_launch(void* const* d_in, const int* in_sizes, int n_in,
                              void* d_out, int out_size, void* d_ws, size_t ws_size,
                              hipStream_t stream)
{
    const int* ids = (const int*)d_in[0];
    const float* emb = (const float*)d_in[1];
    const float* pos = (const float*)d_in[2];
    const float* ln_g = (const float*)d_in[3];
    const float* ln_b = (const float*)d_in[4];
    const float* Wq = (const float*)d_in[5];
    const float* Wk = (const float*)d_in[6];
    const float* Wv = (const float*)d_in[7];
    const float* Wg = (const float*)d_in[8];
    const float* Wo = (const float*)d_in[9];
    const float* W1 = (const float*)d_in[10];
    const float* b1 = (const float*)d_in[11];
    const float* W2 = (const float*)d_in[12];
    const float* b2 = (const float*)d_in[13];
    const float* fcW = (const float*)d_in[14];
    const float* fcb = (const float*)d_in[15];
    float* out = (float*)d_out;

    char* ws = (char*)d_ws;
    u16* WT     = (u16*)(ws);                  //  3,670,016
    u16* x0h    = (u16*)(ws + 3670016);        //  8,388,608  LN(emb) f16 (A + residual)
    u16* Zh     = (u16*)(ws + 12058624);       //  8,388,608  retention out f16
    u16* QKVGh  = (u16*)(ws + 20447232);       // 33,554,432  [8192][2048] f16
    float* fcpart = (float*)(ws + 54001664);   // 32,768
    u16* Sst    = (u16*)(ws + 54034432);       //  4,194,304  [64 bh][8][64][64] f16
    u16* Tst    = (u16*)(ws + 58228736);       //  4,194,304  per-chunk T
    u16* X1h = QKVGh;                           // Wo out (residual for W2)
    u16* Th  = (u16*)((char*)QKVGh + 8388608);  // ln2 out
    u16* Hh  = (u16*)((char*)QKVGh + 16777216); // W1 out
    u16* X2h = Zh;                              // Zh dead after Wo-GEMM

    // only vocab iteration i=2 is live (x overwritten each pass)
    transpose_w<<<dim3(8, 8, 7), 256, 0, stream>>>(Wq, Wk, Wv, Wg, Wo, W1, W2, WT);
    ln_kernel<<<2048, 256, 0, stream>>>(nullptr, ids, emb, pos, ln_g, ln_b, x0h, 1, nullptr, nullptr);
    gemm_f16<<<dim3(16, 64), 256, 0, stream>>>(x0h, WT, QKVGh, nullptr, nullptr, 0, 2048);
    chunk_t<<<512, 256, 0, stream>>>(QKVGh, Tst);
    state_prefix<<<64, 256, 0, stream>>>(Tst, Sst);
    retention_f16<<<512, 256, 0, stream>>>(QKVGh, Sst, Zh);
    gemm_f16<<<dim3(4, 64), 256, 0, stream>>>(Zh, WT + 4 * 262144, X1h, x0h, nullptr, 1, 512);
    ln_kernel<<<2048, 256, 0, stream>>>(X1h, nullptr, nullptr, nullptr, ln_g, ln_b, Th, 0, nullptr, nullptr);
    gemm_f16<<<dim3(4, 64), 256, 0, stream>>>(Th, WT + 5 * 262144, Hh, nullptr, b1, 2, 512);
    gemm_f16<<<dim3(4, 64), 256, 0, stream>>>(Hh, WT + 6 * 262144, X2h, X1h, b2, 3, 512);
    ln_kernel<<<2048, 256, 0, stream>>>(X2h, nullptr, nullptr, nullptr, ln_g, ln_b, nullptr, 0, fcW, fcpart);
    fc_final<<<8, 256, 0, stream>>>(fcpart, fcb, out);
}